// Round 6
// baseline (319.517 us; speedup 1.0000x reference)
//
#include <hip/hip_runtime.h>

// Transformer-XL attention, MI355X gfx950.
// All tensors fp32 in global (per reference); internal path bf16 MFMA + fp32 acc.
// B=4 TQ=1024 TK=1536 D=1024 H=16 DV=64, mem=512 causal: j <= i+512.
//
// Round-13: fused_proj rebalance. Round-12 postmortem: bank conflicts 4.3M->0
// (swizzle verified) but dur flat 72.5us, MfmaUtil 25% -- cost is (A) 1 blk/CU
// so barrier/vmcnt stalls expose fully, (B) KR blocks (K=2048) = 2x V/Q work
// -> 160 CUs idle half the dispatch. Fix: 128x128 tile, 4 waves, same 4-slot
// ring + counted vmcnt(8) (load-count math identical), LDS 64KB -> 2 blocks/CU
// co-resident; 1120 fine-grained blocks (KR 384 | V 384 | Q 256 | bias 96)
// dynamically backfill -> balanced per-CU work + cross-block stall overlap.

typedef unsigned short u16;
typedef __attribute__((ext_vector_type(8))) short short8;   // 8 bf16 (MFMA A/B frag)
typedef __attribute__((ext_vector_type(4))) float floatx4;  // MFMA C/D frag

// 0.125 * log2(e): folded softmax scale so p = 2^(s*SC + bias*SC) via v_exp_f32
#define ATTN_SC 0.18033688011112042f

__device__ __forceinline__ float bf2f(u16 u) {
    union { unsigned int i; float f; } w; w.i = ((unsigned int)u) << 16; return w.f;
}
__device__ __forceinline__ u16 f2bf(float f) {
    union { unsigned int i; float f; } w; w.f = f;
    unsigned int u = w.i;
    return (u16)((u + 0x7FFFu + ((u >> 16) & 1u)) >> 16);
}

// async global->LDS, 16B per lane; LDS dest = wave-uniform base + lane*16
__device__ __forceinline__ void gl_lds16(const u16* g, u16* lds) {
    __builtin_amdgcn_global_load_lds(
        (const __attribute__((address_space(1))) void*)g,
        (__attribute__((address_space(3))) void*)lds, 16, 0, 0);
}

// ---------------------------------------------------------------------------
// Fused fp32 -> bf16 conversion for query/key_value/relative (grid.y selects)
// ---------------------------------------------------------------------------
__global__ __launch_bounds__(256) void cvt3_kernel(
    const float* __restrict__ x0, u16* __restrict__ y0, int n0,
    const float* __restrict__ x1, u16* __restrict__ y1, int n1,
    const float* __restrict__ x2, u16* __restrict__ y2, int n2)
{
    const int which = blockIdx.y;
    const float* x = (which == 0) ? x0 : (which == 1) ? x1 : x2;
    u16* y         = (which == 0) ? y0 : (which == 1) ? y1 : y2;
    const int n    = (which == 0) ? n0 : (which == 1) ? n1 : n2;
    const int i = (blockIdx.x * 256 + threadIdx.x) * 8;
    if (i >= n) return;
    float4 a = *(const float4*)&x[i];
    float4 b = *(const float4*)&x[i + 4];
    short8 o;
    o[0] = (short)f2bf(a.x); o[1] = (short)f2bf(a.y);
    o[2] = (short)f2bf(a.z); o[3] = (short)f2bf(a.w);
    o[4] = (short)f2bf(b.x); o[5] = (short)f2bf(b.y);
    o[6] = (short)f2bf(b.z); o[7] = (short)f2bf(b.w);
    *(short8*)&y[i] = o;
}

// ---------------------------------------------------------------------------
// Fused weight transpose + cvt: 5 weights in one dispatch (grid.z selects).
// WT[n][k] = bf16(W[k][n]); W is 1024x1024 fp32.
// ---------------------------------------------------------------------------
__global__ __launch_bounds__(256) void transpose5_kernel(
    const float* __restrict__ Wq, const float* __restrict__ Wk,
    const float* __restrict__ Wr, const float* __restrict__ Wv,
    const float* __restrict__ Wo,
    u16* __restrict__ WqT, u16* __restrict__ WkrT,
    u16* __restrict__ WvT, u16* __restrict__ WoT)
{
    const int z = blockIdx.z;
    const float* W; u16* WT; int dst_ld, dst_koff;
    switch (z) {
        case 0: W = Wq; WT = WqT;  dst_ld = 1024; dst_koff = 0;    break;
        case 1: W = Wk; WT = WkrT; dst_ld = 2048; dst_koff = 0;    break;
        case 2: W = Wr; WT = WkrT; dst_ld = 2048; dst_koff = 1024; break;
        case 3: W = Wv; WT = WvT;  dst_ld = 1024; dst_koff = 0;    break;
        default:W = Wo; WT = WoT;  dst_ld = 1024; dst_koff = 0;    break;
    }
    __shared__ u16 ts[64][72];
    const int k0 = blockIdx.x * 64, n0 = blockIdx.y * 64;
    const int r  = threadIdx.x >> 2;
    const int c4 = (threadIdx.x & 3) << 4;
    const float* src = &W[(size_t)(k0 + r) * 1024 + n0 + c4];
    for (int j = 0; j < 16; j += 4) {
        float4 a = *(const float4*)(src + j);
        ts[r][c4 + j + 0] = f2bf(a.x);
        ts[r][c4 + j + 1] = f2bf(a.y);
        ts[r][c4 + j + 2] = f2bf(a.z);
        ts[r][c4 + j + 3] = f2bf(a.w);
    }
    __syncthreads();
    short8 t0, t1;
    for (int j = 0; j < 8; j++) t0[j] = (short)ts[c4 + j][r];
    for (int j = 0; j < 8; j++) t1[j] = (short)ts[c4 + 8 + j][r];
    u16* dst = &WT[(size_t)(n0 + r) * dst_ld + dst_koff + k0 + c4];
    *(short8*)dst       = t0;
    *(short8*)(dst + 8) = t1;
}

// ---------------------------------------------------------------------------
// wuvb[h][k] (bf16, [16][2048]): k<1024 -> Wk[k][h*64+:]·u ; else Wr·v
// ---------------------------------------------------------------------------
__global__ __launch_bounds__(256) void wuv_kernel(
    const float* __restrict__ Wk, const float* __restrict__ Wr,
    const float* __restrict__ u, const float* __restrict__ v,
    u16* __restrict__ wuvb)
{
    int idx = blockIdx.x * 256 + threadIdx.x;
    int c = idx >> 4, h = idx & 15;
    float au = 0.f, av = 0.f;
    for (int d = 0; d < 64; d++) {
        au += Wk[(size_t)c * 1024 + h * 64 + d] * u[d];
        av += Wr[(size_t)c * 1024 + h * 64 + d] * v[d];
    }
    wuvb[h * 2048 + c]        = f2bf(au);
    wuvb[h * 2048 + 1024 + c] = f2bf(av);
}

// ---------------------------------------------------------------------------
// Old 128x128 GEMM tile body (m97-style), kept for out_gemm (EPI 3 only):
// raw fp32 out[m*1024 + col] (split-K partial)
// ---------------------------------------------------------------------------
template <int EPI>
__device__ __forceinline__ void gemm_body(
    const u16* __restrict__ A0, const u16* __restrict__ A1,
    const u16* __restrict__ WT, void* __restrict__ out,
    int Kld, int kbeg, int kend, int Ksplit, int T,
    int bm, int bn, u16* As, u16* Ws)
{
    const int tid = threadIdx.x;
    const int wave = tid >> 6, lane = tid & 63;
    const int wm = wave >> 1, wn = wave & 1;
    const int l16 = lane & 15, quad = lane >> 4;

    floatx4 acc[4][4];
    const floatx4 zf = {0.f, 0.f, 0.f, 0.f};
    for (int i = 0; i < 4; i++) for (int j = 0; j < 4; j++) acc[i][j] = zf;

    const int m_base = bm * 128, n_base = bn * 128;
    const int rl = lane >> 2;          // 0..15 row within 16-row DMA group
    const int cl = (lane & 3) * 8;     // 0,8,16,24 col elems (16B)

    for (int k0 = kbeg; k0 < kend; k0 += 32) {
        const u16* Aptr; int kk;
        if (k0 < Ksplit) { Aptr = A0; kk = k0; } else { Aptr = A1; kk = k0 - Ksplit; }
        __syncthreads();
        for (int half = 0; half < 2; half++) {
            const int r = wave * 32 + half * 16;  // wave-uniform LDS base row
            gl_lds16(Aptr + (size_t)(m_base + r + rl) * 1024 + kk + cl, &As[r * 32]);
            gl_lds16(WT   + (size_t)(n_base + r + rl) * Kld  + k0 + cl, &Ws[r * 32]);
        }
        __syncthreads();

        short8 af[4], bf[4];
        for (int i = 0; i < 4; i++) {
            af[i] = *(const short8*)&As[(wm * 64 + i * 16 + l16) * 32 + quad * 8];
            bf[i] = *(const short8*)&Ws[(wn * 64 + i * 16 + l16) * 32 + quad * 8];
        }
        for (int i = 0; i < 4; i++)
            for (int j = 0; j < 4; j++)
                acc[i][j] = __builtin_amdgcn_mfma_f32_16x16x32_bf16(af[i], bf[j], acc[i][j], 0, 0, 0);
    }

    for (int i = 0; i < 4; i++) {
        for (int rg = 0; rg < 4; rg++) {
            const int m = m_base + wm * 64 + i * 16 + quad * 4 + rg;
            float* op = (float*)out;
            for (int j = 0; j < 4; j++) {
                const int col = n_base + wn * 64 + j * 16 + l16;
                op[(size_t)m * 1024 + col] = acc[i][j][rg];
            }
        }
    }
}

// ---------------------------------------------------------------------------
// 128x128 4-wave deep-pipelined GEMM body (round-13).
//   BK=64 = 2 K-halves (ks) of 32 elems. LDS: per matrix a 4-slot ring of
//   [128 rows][32 elems] bf16 (8KB/slot) -> 64KB total -> 2 blocks/CU.
//   Wave grid 2M x 2N: wave tile 64x64, acc 4x4 frags.
//   phase(ph): ks=ph>>1, mh=ph&1 (32-row half of the wave's 64 rows).
//   B frags (4) read at mh0, held in regs for mh1; A frags 2/phase.
//   Stage stream (1 half/phase, 2 gl_lds/wave): ph0 A-ks1(t+1), ph1 B-ks1(t+1),
//   ph2 A-ks0(t+2), ph3 B-ks0(t+2). Slot of (tile,ks) = (2*tile+ks)&3.
//   Sync: vmcnt(8) before entry barrier (completes t,ks0) + vmcnt(8) at end of
//   ph1 (completes t,ks1); vmcnt(0) only at the last tile. setprio around MFMA.
//   T2 swizzle: 16B chunk ^= (row>>1)&3 on stage-source + ds_read (verified
//   conflict-free in round-12: SQ_LDS_BANK_CONFLICT -> 0).
// ---------------------------------------------------------------------------
__device__ __forceinline__ void stage_half128(
    const u16* __restrict__ src, int src_ld, int row_base, int col_base,
    u16* lds_slot, int wave, int lane)
{
    const int r = wave * 16 + (lane >> 2);                        // 0..63 row
    const int c = (((lane & 3) ^ ((lane >> 3) & 3)) << 3);        // pre-swizzled col
    gl_lds16(src + (size_t)(row_base + r) * src_ld + col_base + c,
             lds_slot + wave * 512);
    gl_lds16(src + (size_t)(row_base + 64 + r) * src_ld + col_base + c,
             lds_slot + 2048 + wave * 512);
}

template <int EPI, int T>
__device__ __forceinline__ void gemm128_body(
    const u16* __restrict__ A0, const u16* __restrict__ A1,
    const u16* __restrict__ WT, void* __restrict__ out,
    int Kld, int NT, int KsplitTile, int bm, int bn,
    u16* As, u16* Bs)
{
    const int tid  = threadIdx.x;
    const int wave = tid >> 6, lane = tid & 63;
    const int wm = wave >> 1, wn = wave & 1;       // 2M x 2N wave grid
    const int l16 = lane & 15, quad = lane >> 4;
    const int m_base = bm * 128, n_base = bn * 128;

    floatx4 acc[4][4];
    const floatx4 zf = {0.f, 0.f, 0.f, 0.f};
    #pragma unroll
    for (int i = 0; i < 4; i++)
        #pragma unroll
        for (int j = 0; j < 4; j++) acc[i][j] = zf;

    // --- prologue: 6 halves = tile0 (4) + tile1 ks0 (2) ---
    {
        const u16* sa0 = (0 < KsplitTile) ? A0 : A1;
        stage_half128(sa0, 1024, m_base, 0,  As + 0 * 4096, wave, lane); // A t0 ks0
        stage_half128(WT,  Kld,  n_base, 0,  Bs + 0 * 4096, wave, lane); // B t0 ks0
        stage_half128(sa0, 1024, m_base, 32, As + 1 * 4096, wave, lane); // A t0 ks1
        stage_half128(WT,  Kld,  n_base, 32, Bs + 1 * 4096, wave, lane); // B t0 ks1
        const u16* sa1 = (1 < KsplitTile) ? A0 : A1;
        const int  c1  = (1 < KsplitTile) ? 64 : (1 - KsplitTile) * 64;
        stage_half128(sa1, 1024, m_base, c1, As + 2 * 4096, wave, lane); // A t1 ks0
        stage_half128(WT,  Kld,  n_base, 64, Bs + 2 * 4096, wave, lane); // B t1 ks0
    }

    for (int t = 0; t < NT; ++t) {
        // counted vmcnt before the entry barrier: completes A/B(t,ks0),
        // leaves (t,ks1)+(t+1,ks0) in flight.
        if (t + 1 < NT) asm volatile("s_waitcnt vmcnt(8)" ::: "memory");
        else            asm volatile("s_waitcnt vmcnt(0)" ::: "memory");
        __builtin_amdgcn_s_barrier();

        short8 bfr[4];
        #pragma unroll
        for (int ph = 0; ph < 4; ++ph) {
            if (ph) __builtin_amdgcn_s_barrier();
            const int ks = ph >> 1, mh = ph & 1;

            // ---- stage one half (into a slot freed >=1 barrier ago) ----
            if (ph == 0) {
                if (t + 1 < NT) {
                    const int tt = t + 1;
                    const u16* sa = (tt < KsplitTile) ? A0 : A1;
                    const int cb = (tt < KsplitTile ? tt : tt - KsplitTile) * 64 + 32;
                    stage_half128(sa, 1024, m_base, cb, As + ((2 * tt + 1) & 3) * 4096, wave, lane);
                }
            } else if (ph == 1) {
                if (t + 1 < NT)
                    stage_half128(WT, Kld, n_base, (t + 1) * 64 + 32,
                                  Bs + ((2 * (t + 1) + 1) & 3) * 4096, wave, lane);
            } else if (ph == 2) {
                if (t + 2 < NT) {
                    const int tt = t + 2;
                    const u16* sa = (tt < KsplitTile) ? A0 : A1;
                    const int cb = (tt < KsplitTile ? tt : tt - KsplitTile) * 64;
                    stage_half128(sa, 1024, m_base, cb, As + ((2 * tt) & 3) * 4096, wave, lane);
                }
            } else {
                if (t + 2 < NT)
                    stage_half128(WT, Kld, n_base, (t + 2) * 64,
                                  Bs + ((2 * (t + 2)) & 3) * 4096, wave, lane);
            }

            // ---- ds_read fragments (swizzled: chunk ^= (row>>1)&3) ----
            const u16* Aslot = As + ((2 * t + ks) & 3) * 4096;
            const u16* Bslot = Bs + ((2 * t + ks) & 3) * 4096;
            if (mh == 0) {
                #pragma unroll
                for (int nj = 0; nj < 4; ++nj) {
                    const int row = wn * 64 + nj * 16 + l16;
                    bfr[nj] = *(const short8*)&Bslot[row * 32 + (((quad ^ (row >> 1)) & 3) << 3)];
                }
            }
            short8 af[2];
            #pragma unroll
            for (int mi2 = 0; mi2 < 2; ++mi2) {
                const int row = wm * 64 + mh * 32 + mi2 * 16 + l16;
                af[mi2] = *(const short8*)&Aslot[row * 32 + (((quad ^ (row >> 1)) & 3) << 3)];
            }

            __builtin_amdgcn_s_setprio(1);
            #pragma unroll
            for (int mi2 = 0; mi2 < 2; ++mi2)
                #pragma unroll
                for (int nj = 0; nj < 4; ++nj)
                    acc[mh * 2 + mi2][nj] = __builtin_amdgcn_mfma_f32_16x16x32_bf16(
                        af[mi2], bfr[nj], acc[mh * 2 + mi2][nj], 0, 0, 0);
            __builtin_amdgcn_s_setprio(0);

            // counted vmcnt before ph2's barrier: completes A/B(t,ks1),
            // leaves (t+1,ks0)+(t+1,ks1) in flight.
            if (ph == 1 && t + 1 < NT)
                asm volatile("s_waitcnt vmcnt(8)" ::: "memory");
        }
    }

    // ---- epilogue ----
    u16* op = (u16*)out;
    #pragma unroll
    for (int mi = 0; mi < 4; ++mi) {
        #pragma unroll
        for (int rg = 0; rg < 4; ++rg) {
            const int m = m_base + wm * 64 + mi * 16 + quad * 4 + rg;
            const int b = m / T, tk = m % T;   // T is compile-time -> magic mul
            #pragma unroll
            for (int nj = 0; nj < 4; ++nj) {
                const int col = n_base + wn * 64 + nj * 16 + l16;
                const int h = col >> 6, d = col & 63;
                if (EPI == 0) {
                    op[(((size_t)(b * 16 + h) * T + tk) << 6) + d] = f2bf(acc[mi][nj][rg]);
                } else {  // EPI == 2: head-transposed V^T
                    op[((size_t)(b * 16 + h) * 64 + d) * 1536 + tk] = f2bf(acc[mi][nj][rg]);
                }
            }
        }
    }
}

// ---------------------------------------------------------------------------
// bias body, 4-wave version: [6144,2048]@[2048,16] skinny MFMA, 16 tokens/wave
// 96 blocks x 64 tokens. Output prescaled by ATTN_SC (attn's 1-FMA score).
// ---------------------------------------------------------------------------
__device__ __forceinline__ void bias_body4(
    const u16* __restrict__ kvb, const u16* __restrict__ relb,
    const u16* __restrict__ wuvb, float* __restrict__ bias, int bblk)
{
    const int tid = threadIdx.x;
    const int wave = tid >> 6, lane = tid & 63;
    const int l16 = lane & 15, quad = lane >> 4;
    const int tBase = bblk * 64 + wave * 16;

    floatx4 acc = {0.f, 0.f, 0.f, 0.f};
    const u16* arow_kv  = kvb  + (size_t)(tBase + l16) * 1024;
    const u16* arow_rel = relb + (size_t)(tBase + l16) * 1024;
    const u16* brow     = wuvb + (size_t)l16 * 2048;

    for (int ks = 0; ks < 64; ks++) {
        const int k0 = ks * 32;
        const u16* ap = (k0 < 1024) ? (arow_kv + k0) : (arow_rel + k0 - 1024);
        short8 af = *(const short8*)(ap + quad * 8);
        short8 bf = *(const short8*)(brow + k0 + quad * 8);
        acc = __builtin_amdgcn_mfma_f32_16x16x32_bf16(af, bf, acc, 0, 0, 0);
    }
    for (int rg = 0; rg < 4; rg++) {
        const int tg = tBase + quad * 4 + rg;
        const int b = tg / 1536, t = tg % 1536;
        bias[((size_t)b * 16 + l16) * 1536 + t] = acc[rg] * ATTN_SC;
    }
}

// ---------------------------------------------------------------------------
// Fused projection dispatch v3: 1120 blocks x 256 threads, 2 blocks/CU.
//   (KR 384 | V 384 | Q 256 | bias 96), heavy (K=2048) blocks first.
// ---------------------------------------------------------------------------
__global__ __launch_bounds__(256) void fused_proj_v3(
    const u16* __restrict__ qb, const u16* __restrict__ kvb,
    const u16* __restrict__ relb,
    const u16* __restrict__ WqT, const u16* __restrict__ WkrT,
    const u16* __restrict__ WvT, const u16* __restrict__ wuvb,
    u16* __restrict__ Qh, u16* __restrict__ KRh, u16* __restrict__ Vt,
    float* __restrict__ bias)
{
    __shared__ __align__(128) u16 As[4 * 128 * 32];  // 32KB: 4-slot A ring
    __shared__ __align__(128) u16 Bs[4 * 128 * 32];  // 32KB: 4-slot B ring
    const int blk = blockIdx.x;
    if (blk < 384) {
        // KR: M=6144 K=2048 (kvb tiles 0..15, relb 16..31), T=1536
        gemm128_body<0, 1536>(kvb, relb, WkrT, KRh, 2048, 32, 16,
                              blk % 48, blk / 48, As, Bs);
    } else if (blk < 768) {
        const int i = blk - 384;  // V: M=6144 K=1024, head-transposed out
        gemm128_body<2, 1536>(kvb, kvb, WvT, Vt, 1024, 16, 99,
                              i % 48, i / 48, As, Bs);
    } else if (blk < 1024) {
        const int i = blk - 768;  // Q: M=4096 K=1024, T=1024
        gemm128_body<0, 1024>(qb, qb, WqT, Qh, 1024, 16, 99,
                              i % 32, i / 32, As, Bs);
    } else {
        bias_body4(kvb, relb, wuvb, bias, blk - 1024);
    }
}

// ---------------------------------------------------------------------------
// Output GEMM, split-K=2 (grid (32,8,2) = 512 blocks = 2/CU): raw fp32
// partials to outp + z*4M; LayerNorm sums partials + residual.
// ---------------------------------------------------------------------------
__global__ __launch_bounds__(256) void out_gemm(
    const u16* __restrict__ ctx, const u16* __restrict__ WoT,
    float* __restrict__ outp)
{
    __shared__ u16 smem[2 * 128 * 32];
    const int z = blockIdx.z;
    gemm_body<3>(ctx, nullptr, WoT,
                 outp + (size_t)z * 4 * 1024 * 1024, 1024,
                 z * 512, z * 512 + 512, 1024, 1024,
                 blockIdx.x, blockIdx.y, smem, smem + 128 * 32);
}

// ---------------------------------------------------------------------------
// Flash attention v3 (round-11): LDS-staged K/V via global_load_lds, 2-phase.
// 1024 blocks x 256 thr (4 waves), 4 blocks/CU (LDS 40KB).
// Block = 64 q-rows of one (b,h); wave owns 16 q-rows; all 4 waves share the
// staged 64-key K/V tile. Per tile: {stage(t+1): 4 gl_lds/wave; compute(t)
// from LDS; __syncthreads}. XOR swizzle chunk^=(row&7) on K/V (pre-swizzled
// global source, swizzled ds_read) and on the P scratch (write+read).
// Swapped QK^T (S^T = mfma(K,Q)): score = 1 FMA (bias prescaled by ATTN_SC),
// exp = v_exp_f32, P pack via v_cvt_pk_bf16_f32 + 2x ds_write_b32.
// ---------------------------------------------------------------------------
__global__ __launch_bounds__(256, 4) void attn_kernel(
    const u16* __restrict__ Qh,   // [B][H][1024][64]
    const u16* __restrict__ KRh,  // [B][H][1536][64]
    const u16* __restrict__ Vt,   // [B][H][64][1536]
    const float* __restrict__ bias, // [B][H][1536], prescaled by ATTN_SC
    u16* __restrict__ ctx)        // [B][1024][1024] token-major
{
    const int blk  = blockIdx.x;
    const int hb   = blk & 63;          // XCD-residue swizzle on (b,h)
    const int qb   = blk >> 6;          // 0..15, 64 q-rows per block
    const int b = hb >> 4, h = hb & 15;
    const int tid = threadIdx.x;
    const int wave = tid >> 6, lane = tid & 63;
    const int l16 = lane & 15, quad = lane >> 4;
    const int q0w = qb * 64 + wave * 16;   // this wave's 16 q-rows

    const u16* Qp = Qh  + (size_t)hb * 1024 * 64;
    const u16* Kp = KRh + (size_t)hb * 1536 * 64;
    const u16* Vp = Vt  + (size_t)hb * 64 * 1536;
    const float* bp = bias + (size_t)hb * 1536;

    __shared__ __align__(128) u16 Kbuf[2][64 * 64];  // 16KB  [key][d] swz
    __shared__ __align__(128) u16 Vbuf[2][64 * 64];  // 16KB  [d][key] swz
    __shared__ __align__(128) u16 Ps[4][16 * 64];    // 8KB per-wave P, swz

    // stage one 64x64 u16 tile's wave-owned 16 rows (2 gl_lds of 8 rows).
    // linear LDS dest; source chunk pre-swizzled: phys(row,chunk) holds
    // global (row, chunk ^ (row&7)); row&7 == lane>>3 within each 8-row grp.
    const int srow = lane >> 3;                   // 0..7
    const int scol = ((lane & 7) ^ srow) * 8;     // swizzled source col (elems)

    const floatx4 zf = {0.f, 0.f, 0.f, 0.f};
    floatx4 accO[4];
    float lsum = 0.f;
    #pragma unroll
    for (int j = 0; j < 4; j++) accO[j] = zf;

    short8 aq[2];
    #pragma unroll
    for (int ks = 0; ks < 2; ks++)
        aq[ks] = *(const short8*)
            &Qp[(size_t)(q0w + l16) * 64 + ks * 32 + quad * 8];

    const int nkt = qb + 9;   // tiles cover keys 0 .. qb*64+63+512

    // prologue: stage tile 0 into buf 0
    {
        const int r0 = wave * 16;
        gl_lds16(Kp + (size_t)(r0 + srow) * 64 + scol,        &Kbuf[0][r0 * 64]);
        gl_lds16(Kp + (size_t)(r0 + 8 + srow) * 64 + scol,    &Kbuf[0][(r0 + 8) * 64]);
        gl_lds16(Vp + (size_t)(r0 + srow) * 1536 + scol,      &Vbuf[0][r0 * 64]);
        gl_lds16(Vp + (size_t)(r0 + 8 + srow) * 1536 + scol,  &Vbuf[0][(r0 + 8) * 64]);
    }
    __syncthreads();

    for (int kt = 0; kt < nkt; kt++) {
        const int k0 = kt * 64;
        const int cur = kt & 1;

        // ---- stage tile kt+1 (hides under compute; drained by syncthreads)
        if (kt + 1 < nkt) {
            const int k1 = (kt + 1) * 64;
            const int r0 = wave * 16;
            u16* Kd = &Kbuf[cur ^ 1][0];
            u16* Vd = &Vbuf[cur ^ 1][0];
            gl_lds16(Kp + (size_t)(k1 + r0 + srow) * 64 + scol,       Kd + r0 * 64);
            gl_lds16(Kp + (size_t)(k1 + r0 + 8 + srow) * 64 + scol,   Kd + (r0 + 8) * 64);
            gl_lds16(Vp + (size_t)(r0 + srow) * 1536 + k1 + scol,     Vd + r0 * 64);
            gl_lds16(Vp + (size_t)(r0 + 8 + srow) * 1536 + k1 + scol, Vd + (r0 + 8) * 64);
        }

        // ---- bias for this tile (global, L2/L3-hit; latency overlaps reads)
        float4 bc[4];
        #pragma unroll
        for (int n = 0; n < 4; n++)
            bc[n] = *(const float4*)&bp[k0 + n * 16 + quad * 4];

        // ---- K frags from LDS (swizzled): row = n*16+l16, chunk = ks*4+quad
        const u16* Kb = &Kbuf[cur][0];
        const u16* Vb = &Vbuf[cur][0];
        short8 bk[4][2];
        #pragma unroll
        for (int n = 0; n < 4; n++)
            #pragma unroll
            for (int ks = 0; ks < 2; ks++)
                bk[n][ks] = *(const short8*)
                    &Kb[(n * 16 + l16) * 64 + (((ks * 4 + quad) ^ (l16 & 7)) * 8)];

        // ---- QK^T (swapped): lane q = l16, keys = n*16 + quad*4 + rg
        floatx4 accS[4];
        #pragma unroll
        for (int n = 0; n < 4; n++) {
            accS[n] = zf;
            #pragma unroll
            for (int ks = 0; ks < 2; ks++)
                accS[n] = __builtin_amdgcn_mfma_f32_16x16x32_bf16(
                    bk[n][ks], aq[ks], accS[n], 0, 0, 0);
        }

        // ---- softmax + P pack into swizzled per-wave LDS scratch
        const int qg = q0w + l16;
        const bool domask = (k0 + 63 > q0w + 15 + 512);
        const int lim = qg + 512 - k0;
        char* Pbase = (char*)&Ps[wave][0];
        #pragma unroll
        for (int n = 0; n < 4; n++) {
            const int limn = lim - n * 16 - quad * 4;
            const float* bcn = (const float*)&bc[n];
            float pv[4];
            #pragma unroll
            for (int rg = 0; rg < 4; rg++) {
                float s = fmaf(accS[n][rg], ATTN_SC, bcn[rg]);
                if (domask && rg > limn) s = -1e30f;
                float pe;
                asm("v_exp_f32 %0, %1" : "=v"(pe) : "v"(s));
                lsum += pe;
                pv[rg] = pe;
            }
            unsigned w0, w1;
            asm("v_cvt_pk_bf16_f32 %0, %1, %2" : "=v"(w0) : "v"(pv[0]), "v"(pv[1]));
            asm("v_cvt_pk_bf16_f32 %0, %1, %2" : "=v"(w1) : "v"(pv[2]), "v"(pv[3]));
            // logical byte = l16*128 + n*32 + quad*8 ; phys ^= (l16&7)<<4
            unsigned* pw = (unsigned*)(Pbase +
                (((l16 * 128 + n * 32 + quad * 8)) ^ ((l16 & 7) << 4)));
            pw[0] = w0; pw[1] = w1;
        }

        // ---- PV: A frag = P row l16 (swizzled b128), B frag = V from LDS
        short8 ap[2];
        #pragma unroll
        for (int ks = 0; ks < 2; ks++)
            ap[ks] = *(const short8*)(Pbase +
                (((l16 * 128 + ks * 64 + quad * 16)) ^ ((l16 & 7) << 4)));
        #pragma unroll
        for (int j = 0; j < 4; j++) {
            #pragma unroll
            for (int ks = 0; ks < 2; ks++) {
                short8 bv = *(const short8*)
                    &Vb[(j * 16 + l16) * 64 + (((ks * 4 + quad) ^ (l16 & 7)) * 8)];
                accO[j] = __builtin_amdgcn_mfma_f32_16x16x32_bf16(
                    ap[ks], bv, accO[j], 0, 0, 0);
            }
        }

        __syncthreads();   // drains stage(kt+1) vmcnt + guards buffer reuse
    }

    // lsum quad-reduce: every lane gets full sum for q = l16
    {
        float s = lsum;
        s += __shfl_xor(s, 16, 64);
        s += __shfl_xor(s, 32, 64);
        lsum = s;
    }
    float ltr[4];
    #pragma unroll
    for (int rg = 0; rg < 4; rg++)
        ltr[rg] = __shfl(lsum, quad * 4 + rg, 16);   // sum for q = quad*4+rg

    #pragma unroll
    for (int j = 0; j < 4; j++)
        #pragma unroll
        for (int rg = 0; rg < 4; rg++) {
            const int q = q0w + quad * 4 + rg;
            const int d = j * 16 + l16;
            ctx[((size_t)b * 1024 + q) * 1024 + h * 64 + d] =
                f2bf(accO[j][rg] / ltr[rg]);
        }
}

// ---------------------------------------------------------------------------
// LayerNorm over (partial0 + partial1 + residual query): fp32 -> fp32 d_out
// ---------------------------------------------------------------------------
__global__ __launch_bounds__(256) void ln_kernel(
    const float* __restrict__ x0, const float* __restrict__ x1,
    const float* __restrict__ q,
    const float* __restrict__ gamma, const float* __restrict__ beta,
    float* __restrict__ out)
{
    const int row = blockIdx.x;
    const int tid = threadIdx.x;
    const size_t base = (size_t)row * 1024 + tid * 4;
    float4 a = *(const float4*)&x0[base];
    float4 c = *(const float4*)&x1[base];
    float4 r = *(const float4*)&q[base];
    float4 v;
    v.x = a.x + c.x + r.x; v.y = a.y + c.y + r.y;
    v.z = a.z + c.z + r.z; v.w = a.w + c.w + r.w;
    float s  = v.x + v.y + v.z + v.w;
    float ss = v.x * v.x + v.y * v.y + v.z * v.z + v.w * v.w;
    for (int off = 1; off < 64; off <<= 1) {
        s  += __shfl_xor(s, off, 64);
        ss += __shfl_xor(ss, off, 64);
    }
    __shared__ float sm[8];
    const int wave = tid >> 6, lane = tid & 63;
    if (lane == 0) { sm[wave] = s; sm[4 + wave] = ss; }
    __syncthreads();
    s  = sm[0] + sm[1] + sm[2] + sm[3];
    ss = sm[4] + sm[5] + sm[6] + sm[7];
    const float mu  = s * (1.f / 1024.f);
    const float var = ss * (1.f / 1024.f) - mu * mu;
    const float inv = rsqrtf(var + 1e-5f);
    float* op = out + (size_t)row * 1024;
    const float* ve = &v.x;
    for (int j = 0; j < 4; j++) {
        const int c2 = tid * 4 + j;
        op[c2] = (ve[j] - mu) * inv * gamma[c2] + beta[c2];
    }
}

// ---------------------------------------------------------------------------
extern "C" void kernel_launch(void* const* d_in, const int* in_sizes, int n_in,
                              void* d_out, int out_size, void* d_ws, size_t ws_size,
                              hipStream_t stream)
{
    const float* query     = (const float*)d_in[0];
    const float* key_value = (const float*)d_in[1];
    const float* relative  = (const float*)d_in[2];
    // d_in[3] = mask: analytic (j <= i+512), unused
    const float* Wq = (const float*)d_in[4];
    const float* Wk = (const float*)d_in[5];
    const float* Wv = (const float*)d_in[6];
    const float* Wr = (const float*)d_in[7];
    const float* Wo = (const float*)d_in[8];
    const float* u  = (const float*)d_in[9];
    const float* v  = (const float*)d_in[10];
    const float* gamma = (const float*)d_in[11];
    const float* beta  = (const float*)d_in[12];

    char* wsp = (char*)d_ws;
    auto alloc = [&](size_t bytes) -> char* {
        char* p = wsp; wsp += (bytes + 255) & ~(size_t)255; return p;
    };
    u16*   qb   = (u16*)alloc((size_t)4 * 1024 * 1024 * 2);
    u16*   kvb  = (u16*)alloc((size_t)4 * 1536 * 1024 * 2);
    u16*   relb = (u16*)alloc((size_t)4 * 1536 * 1024 * 2);
    u16*   WqT  = (u16*)alloc((size_t)1024 * 1024 * 2);
    u16*   WkrT = (u16*)alloc((size_t)1024 * 2048 * 2);
    u16*   WvT  = (u16*)alloc((size_t)1024 * 1024 * 2);
    u16*   WoT  = (u16*)alloc((size_t)1024 * 1024 * 2);
    u16*   wuvb = (u16*)alloc((size_t)16 * 2048 * 2);
    u16*   Qh   = (u16*)alloc((size_t)4 * 16 * 1024 * 64 * 2);
    u16*   KRh  = (u16*)alloc((size_t)4 * 16 * 1536 * 64 * 2);
    u16*   Vt   = (u16*)alloc((size_t)4 * 16 * 64 * 1536 * 2);
    float* bias = (float*)alloc((size_t)4 * 16 * 1536 * 4);
    u16*   ctx  = (u16*)alloc((size_t)4 * 1024 * 1024 * 2);
    float* outp = (float*)alloc((size_t)2 * 4 * 1024 * 1024 * 4);  // 2 split-K partials

    const dim3 tb(256);
    cvt3_kernel<<<dim3(3072, 3), tb, 0, stream>>>(
        query, qb, 4 * 1024 * 1024,
        key_value, kvb, 4 * 1536 * 1024,
        relative, relb, 4 * 1536 * 1024);

    transpose5_kernel<<<dim3(16, 16, 5), tb, 0, stream>>>(
        Wq, Wk, Wr, Wv, Wo, WqT, WkrT, WvT, WoT);
    wuv_kernel<<<64, tb, 0, stream>>>(Wk, Wr, u, v, wuvb);

    fused_proj_v3<<<dim3(1120), tb, 0, stream>>>(
        qb, kvb, relb, WqT, WkrT, WvT, wuvb, Qh, KRh, Vt, bias);

    attn_kernel<<<dim3(1024), tb, 0, stream>>>(Qh, KRh, Vt, bias, ctx);

    out_gemm<<<dim3(32, 8, 2), tb, 0, stream>>>(ctx, WoT, outp);
    ln_kernel<<<4096, tb, 0, stream>>>(
        outp, outp + (size_t)4 * 1024 * 1024, query, gamma, beta, (float*)d_out);
}

// Round 7
// 303.182 us; speedup vs baseline: 1.0539x; 1.0539x over previous
//
#include <hip/hip_runtime.h>

// Transformer-XL attention, MI355X gfx950.
// All tensors fp32 in global (per reference); internal path bf16 MFMA + fp32 acc.
// B=4 TQ=1024 TK=1536 D=1024 H=16 DV=64, mem=512 causal: j <= i+512.
//
// Round-14: revert round-13's 128^2 tile (100us regression: per-phase overhead
// doubled, MfmaUtil 19%). Back to round-12's 256^2 body (72.5us) PLUS the m201
// double-barrier phase sandwich: {ds_read frags; stage; barrier; setprio+MFMA;
// counted vmcnt; barrier}. Waits re-derived for new positions: steady-state
// outstanding=12 at each wait, vmcnt(8) completes exactly the target half;
// end-of-ph1 completes (t,ks1), end-of-ph3 completes (t+1,ks0); tails
// vmcnt(0)/vmcnt(4); prologue vmcnt(8)+barrier covers ph0's (t0,ks0) read.

typedef unsigned short u16;
typedef __attribute__((ext_vector_type(8))) short short8;   // 8 bf16 (MFMA A/B frag)
typedef __attribute__((ext_vector_type(4))) float floatx4;  // MFMA C/D frag

// 0.125 * log2(e): folded softmax scale so p = 2^(s*SC + bias*SC) via v_exp_f32
#define ATTN_SC 0.18033688011112042f

__device__ __forceinline__ float bf2f(u16 u) {
    union { unsigned int i; float f; } w; w.i = ((unsigned int)u) << 16; return w.f;
}
__device__ __forceinline__ u16 f2bf(float f) {
    union { unsigned int i; float f; } w; w.f = f;
    unsigned int u = w.i;
    return (u16)((u + 0x7FFFu + ((u >> 16) & 1u)) >> 16);
}

// async global->LDS, 16B per lane; LDS dest = wave-uniform base + lane*16
__device__ __forceinline__ void gl_lds16(const u16* g, u16* lds) {
    __builtin_amdgcn_global_load_lds(
        (const __attribute__((address_space(1))) void*)g,
        (__attribute__((address_space(3))) void*)lds, 16, 0, 0);
}

// ---------------------------------------------------------------------------
// Fused fp32 -> bf16 conversion for query/key_value/relative (grid.y selects)
// ---------------------------------------------------------------------------
__global__ __launch_bounds__(256) void cvt3_kernel(
    const float* __restrict__ x0, u16* __restrict__ y0, int n0,
    const float* __restrict__ x1, u16* __restrict__ y1, int n1,
    const float* __restrict__ x2, u16* __restrict__ y2, int n2)
{
    const int which = blockIdx.y;
    const float* x = (which == 0) ? x0 : (which == 1) ? x1 : x2;
    u16* y         = (which == 0) ? y0 : (which == 1) ? y1 : y2;
    const int n    = (which == 0) ? n0 : (which == 1) ? n1 : n2;
    const int i = (blockIdx.x * 256 + threadIdx.x) * 8;
    if (i >= n) return;
    float4 a = *(const float4*)&x[i];
    float4 b = *(const float4*)&x[i + 4];
    short8 o;
    o[0] = (short)f2bf(a.x); o[1] = (short)f2bf(a.y);
    o[2] = (short)f2bf(a.z); o[3] = (short)f2bf(a.w);
    o[4] = (short)f2bf(b.x); o[5] = (short)f2bf(b.y);
    o[6] = (short)f2bf(b.z); o[7] = (short)f2bf(b.w);
    *(short8*)&y[i] = o;
}

// ---------------------------------------------------------------------------
// Fused weight transpose + cvt: 5 weights in one dispatch (grid.z selects).
// WT[n][k] = bf16(W[k][n]); W is 1024x1024 fp32.
// ---------------------------------------------------------------------------
__global__ __launch_bounds__(256) void transpose5_kernel(
    const float* __restrict__ Wq, const float* __restrict__ Wk,
    const float* __restrict__ Wr, const float* __restrict__ Wv,
    const float* __restrict__ Wo,
    u16* __restrict__ WqT, u16* __restrict__ WkrT,
    u16* __restrict__ WvT, u16* __restrict__ WoT)
{
    const int z = blockIdx.z;
    const float* W; u16* WT; int dst_ld, dst_koff;
    switch (z) {
        case 0: W = Wq; WT = WqT;  dst_ld = 1024; dst_koff = 0;    break;
        case 1: W = Wk; WT = WkrT; dst_ld = 2048; dst_koff = 0;    break;
        case 2: W = Wr; WT = WkrT; dst_ld = 2048; dst_koff = 1024; break;
        case 3: W = Wv; WT = WvT;  dst_ld = 1024; dst_koff = 0;    break;
        default:W = Wo; WT = WoT;  dst_ld = 1024; dst_koff = 0;    break;
    }
    __shared__ u16 ts[64][72];
    const int k0 = blockIdx.x * 64, n0 = blockIdx.y * 64;
    const int r  = threadIdx.x >> 2;
    const int c4 = (threadIdx.x & 3) << 4;
    const float* src = &W[(size_t)(k0 + r) * 1024 + n0 + c4];
    for (int j = 0; j < 16; j += 4) {
        float4 a = *(const float4*)(src + j);
        ts[r][c4 + j + 0] = f2bf(a.x);
        ts[r][c4 + j + 1] = f2bf(a.y);
        ts[r][c4 + j + 2] = f2bf(a.z);
        ts[r][c4 + j + 3] = f2bf(a.w);
    }
    __syncthreads();
    short8 t0, t1;
    for (int j = 0; j < 8; j++) t0[j] = (short)ts[c4 + j][r];
    for (int j = 0; j < 8; j++) t1[j] = (short)ts[c4 + 8 + j][r];
    u16* dst = &WT[(size_t)(n0 + r) * dst_ld + dst_koff + k0 + c4];
    *(short8*)dst       = t0;
    *(short8*)(dst + 8) = t1;
}

// ---------------------------------------------------------------------------
// wuvb[h][k] (bf16, [16][2048]): k<1024 -> Wk[k][h*64+:]·u ; else Wr·v
// ---------------------------------------------------------------------------
__global__ __launch_bounds__(256) void wuv_kernel(
    const float* __restrict__ Wk, const float* __restrict__ Wr,
    const float* __restrict__ u, const float* __restrict__ v,
    u16* __restrict__ wuvb)
{
    int idx = blockIdx.x * 256 + threadIdx.x;
    int c = idx >> 4, h = idx & 15;
    float au = 0.f, av = 0.f;
    for (int d = 0; d < 64; d++) {
        au += Wk[(size_t)c * 1024 + h * 64 + d] * u[d];
        av += Wr[(size_t)c * 1024 + h * 64 + d] * v[d];
    }
    wuvb[h * 2048 + c]        = f2bf(au);
    wuvb[h * 2048 + 1024 + c] = f2bf(av);
}

// ---------------------------------------------------------------------------
// Old 128x128 GEMM tile body (m97-style), kept for out_gemm (EPI 3 only):
// raw fp32 out[m*1024 + col] (split-K partial)
// ---------------------------------------------------------------------------
template <int EPI>
__device__ __forceinline__ void gemm_body(
    const u16* __restrict__ A0, const u16* __restrict__ A1,
    const u16* __restrict__ WT, void* __restrict__ out,
    int Kld, int kbeg, int kend, int Ksplit, int T,
    int bm, int bn, u16* As, u16* Ws)
{
    const int tid = threadIdx.x;
    const int wave = tid >> 6, lane = tid & 63;
    const int wm = wave >> 1, wn = wave & 1;
    const int l16 = lane & 15, quad = lane >> 4;

    floatx4 acc[4][4];
    const floatx4 zf = {0.f, 0.f, 0.f, 0.f};
    for (int i = 0; i < 4; i++) for (int j = 0; j < 4; j++) acc[i][j] = zf;

    const int m_base = bm * 128, n_base = bn * 128;
    const int rl = lane >> 2;          // 0..15 row within 16-row DMA group
    const int cl = (lane & 3) * 8;     // 0,8,16,24 col elems (16B)

    for (int k0 = kbeg; k0 < kend; k0 += 32) {
        const u16* Aptr; int kk;
        if (k0 < Ksplit) { Aptr = A0; kk = k0; } else { Aptr = A1; kk = k0 - Ksplit; }
        __syncthreads();
        for (int half = 0; half < 2; half++) {
            const int r = wave * 32 + half * 16;  // wave-uniform LDS base row
            gl_lds16(Aptr + (size_t)(m_base + r + rl) * 1024 + kk + cl, &As[r * 32]);
            gl_lds16(WT   + (size_t)(n_base + r + rl) * Kld  + k0 + cl, &Ws[r * 32]);
        }
        __syncthreads();

        short8 af[4], bf[4];
        for (int i = 0; i < 4; i++) {
            af[i] = *(const short8*)&As[(wm * 64 + i * 16 + l16) * 32 + quad * 8];
            bf[i] = *(const short8*)&Ws[(wn * 64 + i * 16 + l16) * 32 + quad * 8];
        }
        for (int i = 0; i < 4; i++)
            for (int j = 0; j < 4; j++)
                acc[i][j] = __builtin_amdgcn_mfma_f32_16x16x32_bf16(af[i], bf[j], acc[i][j], 0, 0, 0);
    }

    for (int i = 0; i < 4; i++) {
        for (int rg = 0; rg < 4; rg++) {
            const int m = m_base + wm * 64 + i * 16 + quad * 4 + rg;
            float* op = (float*)out;
            for (int j = 0; j < 4; j++) {
                const int col = n_base + wn * 64 + j * 16 + l16;
                op[(size_t)m * 1024 + col] = acc[i][j][rg];
            }
        }
    }
}

// ---------------------------------------------------------------------------
// 256x256 8-wave deep-pipelined GEMM body (m201-template phase sandwich).
//   BK=64 = 2 K-halves (ks) of 32 elems. LDS: per matrix a 4-slot ring of
//   [256 rows][32 elems] bf16 (16KB/slot) -> 128KB total, 1 block/CU.
//   phase(ph): ks=ph>>1, mh=ph&1. B frags read at mh0, held in regs for mh1.
//   Phase body (m201 sandwich): {ds_read frags; stage 1 half; s_barrier;
//   setprio(1) MFMA x16 setprio(0); [counted vmcnt]; s_barrier}.
//   Stage stream: ph0 A-ks1(t+1), ph1 B-ks1(t+1), ph2 A-ks0(t+2),
//   ph3 B-ks0(t+2). Slot of (tile,ks) = (2*tile+ks)&3.
//   Waits (per-wave FIFO, 2 loads per stage_half, steady outstanding = 12):
//     end-of-ph1: vmcnt(8) completes (t,ks1)   [vmcnt(0) if t+1==NT]
//     end-of-ph3: vmcnt(8) completes (t+1,ks0) [vmcnt(4) if t+2==NT; skip at last]
//   both BEFORE barrier-B -> staged data cross-wave visible for next phase's
//   ds_read. Prologue: 6 halves, vmcnt(8) completes (t0,ks0), barrier.
//   T2 swizzle: 16B chunk ^= (row>>1)&3 on stage-source + ds_read (round-12
//   verified: SQ_LDS_BANK_CONFLICT -> 0).
// ---------------------------------------------------------------------------
__device__ __forceinline__ void stage_half(
    const u16* __restrict__ src, int src_ld, int row_base, int col_base,
    u16* lds_slot, int wave, int lane)
{
    const int r = wave * 16 + (lane >> 2);                        // row in half
    const int c = (((lane & 3) ^ ((lane >> 3) & 3)) << 3);        // pre-swizzled col
    gl_lds16(src + (size_t)(row_base + r) * src_ld + col_base + c,
             lds_slot + wave * 512);
    gl_lds16(src + (size_t)(row_base + 128 + r) * src_ld + col_base + c,
             lds_slot + 4096 + wave * 512);
}

template <int EPI, int T>
__device__ __forceinline__ void gemm256_body(
    const u16* __restrict__ A0, const u16* __restrict__ A1,
    const u16* __restrict__ WT, void* __restrict__ out,
    int Kld, int NT, int KsplitTile, int bm, int bn,
    u16* As, u16* Bs)
{
    const int tid  = threadIdx.x;
    const int wave = tid >> 6, lane = tid & 63;
    const int wm = wave >> 2, wn = wave & 3;       // 2M x 4N wave grid
    const int l16 = lane & 15, quad = lane >> 4;
    const int m_base = bm * 256, n_base = bn * 256;

    floatx4 acc[8][4];
    const floatx4 zf = {0.f, 0.f, 0.f, 0.f};
    #pragma unroll
    for (int i = 0; i < 8; i++)
        #pragma unroll
        for (int j = 0; j < 4; j++) acc[i][j] = zf;

    // --- prologue: 6 halves = tile0 (4) + tile1 ks0 (2) ---
    {
        const u16* sa0 = (0 < KsplitTile) ? A0 : A1;
        stage_half(sa0, 1024, m_base, 0,  As + 0 * 8192, wave, lane); // A t0 ks0
        stage_half(WT,  Kld,  n_base, 0,  Bs + 0 * 8192, wave, lane); // B t0 ks0
        stage_half(sa0, 1024, m_base, 32, As + 1 * 8192, wave, lane); // A t0 ks1
        stage_half(WT,  Kld,  n_base, 32, Bs + 1 * 8192, wave, lane); // B t0 ks1
        const u16* sa1 = (1 < KsplitTile) ? A0 : A1;
        const int  c1  = (1 < KsplitTile) ? 64 : (1 - KsplitTile) * 64;
        stage_half(sa1, 1024, m_base, c1, As + 2 * 8192, wave, lane); // A t1 ks0
        stage_half(WT,  Kld,  n_base, 64, Bs + 2 * 8192, wave, lane); // B t1 ks0
    }
    // completes (t0,ks0) A+B; leaves 8 in flight
    asm volatile("s_waitcnt vmcnt(8)" ::: "memory");
    __builtin_amdgcn_s_barrier();

    for (int t = 0; t < NT; ++t) {
        short8 bfr[4];
        #pragma unroll
        for (int ph = 0; ph < 4; ++ph) {
            const int ks = ph >> 1, mh = ph & 1;

            // ---- 1. ds_read fragments (visible: prior vmcnt+barrier) ----
            const u16* Aslot = As + ((2 * t + ks) & 3) * 8192;
            const u16* Bslot = Bs + ((2 * t + ks) & 3) * 8192;
            if (mh == 0) {
                #pragma unroll
                for (int nj = 0; nj < 4; ++nj) {
                    const int row = wn * 64 + nj * 16 + l16;
                    bfr[nj] = *(const short8*)&Bslot[row * 32 + (((quad ^ (row >> 1)) & 3) << 3)];
                }
            }
            short8 af[4];
            #pragma unroll
            for (int mi = 0; mi < 4; ++mi) {
                const int row = wm * 128 + mh * 64 + mi * 16 + l16;
                af[mi] = *(const short8*)&Aslot[row * 32 + (((quad ^ (row >> 1)) & 3) << 3)];
            }

            // ---- 2. stage one half (slot freed >=1 barrier ago) ----
            if (ph == 0) {
                if (t + 1 < NT) {
                    const int tt = t + 1;
                    const u16* sa = (tt < KsplitTile) ? A0 : A1;
                    const int cb = (tt < KsplitTile ? tt : tt - KsplitTile) * 64 + 32;
                    stage_half(sa, 1024, m_base, cb, As + ((2 * tt + 1) & 3) * 8192, wave, lane);
                }
            } else if (ph == 1) {
                if (t + 1 < NT)
                    stage_half(WT, Kld, n_base, (t + 1) * 64 + 32,
                               Bs + ((2 * (t + 1) + 1) & 3) * 8192, wave, lane);
            } else if (ph == 2) {
                if (t + 2 < NT) {
                    const int tt = t + 2;
                    const u16* sa = (tt < KsplitTile) ? A0 : A1;
                    const int cb = (tt < KsplitTile ? tt : tt - KsplitTile) * 64;
                    stage_half(sa, 1024, m_base, cb, As + ((2 * tt) & 3) * 8192, wave, lane);
                }
            } else {
                if (t + 2 < NT)
                    stage_half(WT, Kld, n_base, (t + 2) * 64,
                               Bs + ((2 * (t + 2)) & 3) * 8192, wave, lane);
            }

            // ---- 3. barrier A: cluster LDS reads, release MFMA wave-front ----
            __builtin_amdgcn_s_barrier();

            // ---- 4. MFMA cluster ----
            __builtin_amdgcn_s_setprio(1);
            #pragma unroll
            for (int mi = 0; mi < 4; ++mi)
                #pragma unroll
                for (int nj = 0; nj < 4; ++nj)
                    acc[mh * 4 + mi][nj] = __builtin_amdgcn_mfma_f32_16x16x32_bf16(
                        af[mi], bfr[nj], acc[mh * 4 + mi][nj], 0, 0, 0);
            __builtin_amdgcn_s_setprio(0);

            // ---- 5. counted vmcnt (before barrier B -> cross-wave visible) ----
            if (ph == 1) {
                if (t + 1 < NT) asm volatile("s_waitcnt vmcnt(8)" ::: "memory");
                else            asm volatile("s_waitcnt vmcnt(0)" ::: "memory");
            } else if (ph == 3) {
                if (t + 2 < NT)      asm volatile("s_waitcnt vmcnt(8)" ::: "memory");
                else if (t + 1 < NT) asm volatile("s_waitcnt vmcnt(4)" ::: "memory");
            }
            __builtin_amdgcn_s_barrier();
        }
    }

    // ---- epilogue ----
    u16* op = (u16*)out;
    #pragma unroll
    for (int mi = 0; mi < 8; ++mi) {
        #pragma unroll
        for (int rg = 0; rg < 4; ++rg) {
            const int m = m_base + wm * 128 + mi * 16 + quad * 4 + rg;
            const int b = m / T, tk = m % T;   // T is compile-time -> magic mul
            #pragma unroll
            for (int nj = 0; nj < 4; ++nj) {
                const int col = n_base + wn * 64 + nj * 16 + l16;
                const int h = col >> 6, d = col & 63;
                if (EPI == 0) {
                    op[(((size_t)(b * 16 + h) * T + tk) << 6) + d] = f2bf(acc[mi][nj][rg]);
                } else {  // EPI == 2: head-transposed V^T
                    op[((size_t)(b * 16 + h) * 64 + d) * 1536 + tk] = f2bf(acc[mi][nj][rg]);
                }
            }
        }
    }
}

// ---------------------------------------------------------------------------
// bias body, 8-wave version: [6144,2048]@[2048,16] skinny MFMA, 16 tokens/wave
// Output prescaled by ATTN_SC (softmax scale+log2e fold for attn's 1-FMA score).
// ---------------------------------------------------------------------------
__device__ __forceinline__ void bias_body8(
    const u16* __restrict__ kvb, const u16* __restrict__ relb,
    const u16* __restrict__ wuvb, float* __restrict__ bias, int bblk)
{
    const int tid = threadIdx.x;
    const int wave = tid >> 6, lane = tid & 63;
    const int l16 = lane & 15, quad = lane >> 4;
    const int tBase = bblk * 128 + wave * 16;

    floatx4 acc = {0.f, 0.f, 0.f, 0.f};
    const u16* arow_kv  = kvb  + (size_t)(tBase + l16) * 1024;
    const u16* arow_rel = relb + (size_t)(tBase + l16) * 1024;
    const u16* brow     = wuvb + (size_t)l16 * 2048;

    for (int ks = 0; ks < 64; ks++) {
        const int k0 = ks * 32;
        const u16* ap = (k0 < 1024) ? (arow_kv + k0) : (arow_rel + k0 - 1024);
        short8 af = *(const short8*)(ap + quad * 8);
        short8 bf = *(const short8*)(brow + k0 + quad * 8);
        acc = __builtin_amdgcn_mfma_f32_16x16x32_bf16(af, bf, acc, 0, 0, 0);
    }
    for (int rg = 0; rg < 4; rg++) {
        const int tg = tBase + quad * 4 + rg;
        const int b = tg / 1536, t = tg % 1536;
        bias[((size_t)b * 16 + l16) * 1536 + t] = acc[rg] * ATTN_SC;
    }
}

// ---------------------------------------------------------------------------
// Fused projection dispatch v2: 304 blocks x 512 threads
//   (KR 96 | V 96 | Q 64 | bias 48), heavy (K=2048) blocks first.
// ---------------------------------------------------------------------------
__global__ __launch_bounds__(512) void fused_proj_v2(
    const u16* __restrict__ qb, const u16* __restrict__ kvb,
    const u16* __restrict__ relb,
    const u16* __restrict__ WqT, const u16* __restrict__ WkrT,
    const u16* __restrict__ WvT, const u16* __restrict__ wuvb,
    u16* __restrict__ Qh, u16* __restrict__ KRh, u16* __restrict__ Vt,
    float* __restrict__ bias)
{
    __shared__ __align__(128) u16 As[4 * 256 * 32];  // 64KB: 4-slot A ring
    __shared__ __align__(128) u16 Bs[4 * 256 * 32];  // 64KB: 4-slot B ring
    const int blk = blockIdx.x;
    if (blk < 96) {
        // KR: M=6144 K=2048 (kvb tiles 0..15, relb 16..31), T=1536
        gemm256_body<0, 1536>(kvb, relb, WkrT, KRh, 2048, 32, 16,
                              blk % 24, blk / 24, As, Bs);
    } else if (blk < 192) {
        const int i = blk - 96;   // V: M=6144 K=1024, head-transposed out
        gemm256_body<2, 1536>(kvb, kvb, WvT, Vt, 1024, 16, 99,
                              i % 24, i / 24, As, Bs);
    } else if (blk < 256) {
        const int i = blk - 192;  // Q: M=4096 K=1024, T=1024
        gemm256_body<0, 1024>(qb, qb, WqT, Qh, 1024, 16, 99,
                              i % 16, i / 16, As, Bs);
    } else {
        bias_body8(kvb, relb, wuvb, bias, blk - 256);
    }
}

// ---------------------------------------------------------------------------
// Output GEMM, split-K=2 (grid (32,8,2) = 512 blocks = 2/CU): raw fp32
// partials to outp + z*4M; LayerNorm sums partials + residual.
// ---------------------------------------------------------------------------
__global__ __launch_bounds__(256) void out_gemm(
    const u16* __restrict__ ctx, const u16* __restrict__ WoT,
    float* __restrict__ outp)
{
    __shared__ u16 smem[2 * 128 * 32];
    const int z = blockIdx.z;
    gemm_body<3>(ctx, nullptr, WoT,
                 outp + (size_t)z * 4 * 1024 * 1024, 1024,
                 z * 512, z * 512 + 512, 1024, 1024,
                 blockIdx.x, blockIdx.y, smem, smem + 128 * 32);
}

// ---------------------------------------------------------------------------
// Flash attention v3 (round-11): LDS-staged K/V via global_load_lds, 2-phase.
// 1024 blocks x 256 thr (4 waves), 4 blocks/CU (LDS 40KB).
// Block = 64 q-rows of one (b,h); wave owns 16 q-rows; all 4 waves share the
// staged 64-key K/V tile. Per tile: {stage(t+1): 4 gl_lds/wave; compute(t)
// from LDS; __syncthreads}. XOR swizzle chunk^=(row&7) on K/V (pre-swizzled
// global source, swizzled ds_read) and on the P scratch (write+read).
// Swapped QK^T (S^T = mfma(K,Q)): score = 1 FMA (bias prescaled by ATTN_SC),
// exp = v_exp_f32, P pack via v_cvt_pk_bf16_f32 + 2x ds_write_b32.
// ---------------------------------------------------------------------------
__global__ __launch_bounds__(256, 4) void attn_kernel(
    const u16* __restrict__ Qh,   // [B][H][1024][64]
    const u16* __restrict__ KRh,  // [B][H][1536][64]
    const u16* __restrict__ Vt,   // [B][H][64][1536]
    const float* __restrict__ bias, // [B][H][1536], prescaled by ATTN_SC
    u16* __restrict__ ctx)        // [B][1024][1024] token-major
{
    const int blk  = blockIdx.x;
    const int hb   = blk & 63;          // XCD-residue swizzle on (b,h)
    const int qb   = blk >> 6;          // 0..15, 64 q-rows per block
    const int b = hb >> 4, h = hb & 15;
    const int tid = threadIdx.x;
    const int wave = tid >> 6, lane = tid & 63;
    const int l16 = lane & 15, quad = lane >> 4;
    const int q0w = qb * 64 + wave * 16;   // this wave's 16 q-rows

    const u16* Qp = Qh  + (size_t)hb * 1024 * 64;
    const u16* Kp = KRh + (size_t)hb * 1536 * 64;
    const u16* Vp = Vt  + (size_t)hb * 64 * 1536;
    const float* bp = bias + (size_t)hb * 1536;

    __shared__ __align__(128) u16 Kbuf[2][64 * 64];  // 16KB  [key][d] swz
    __shared__ __align__(128) u16 Vbuf[2][64 * 64];  // 16KB  [d][key] swz
    __shared__ __align__(128) u16 Ps[4][16 * 64];    // 8KB per-wave P, swz

    // stage one 64x64 u16 tile's wave-owned 16 rows (2 gl_lds of 8 rows).
    // linear LDS dest; source chunk pre-swizzled: phys(row,chunk) holds
    // global (row, chunk ^ (row&7)); row&7 == lane>>3 within each 8-row grp.
    const int srow = lane >> 3;                   // 0..7
    const int scol = ((lane & 7) ^ srow) * 8;     // swizzled source col (elems)

    const floatx4 zf = {0.f, 0.f, 0.f, 0.f};
    floatx4 accO[4];
    float lsum = 0.f;
    #pragma unroll
    for (int j = 0; j < 4; j++) accO[j] = zf;

    short8 aq[2];
    #pragma unroll
    for (int ks = 0; ks < 2; ks++)
        aq[ks] = *(const short8*)
            &Qp[(size_t)(q0w + l16) * 64 + ks * 32 + quad * 8];

    const int nkt = qb + 9;   // tiles cover keys 0 .. qb*64+63+512

    // prologue: stage tile 0 into buf 0
    {
        const int r0 = wave * 16;
        gl_lds16(Kp + (size_t)(r0 + srow) * 64 + scol,        &Kbuf[0][r0 * 64]);
        gl_lds16(Kp + (size_t)(r0 + 8 + srow) * 64 + scol,    &Kbuf[0][(r0 + 8) * 64]);
        gl_lds16(Vp + (size_t)(r0 + srow) * 1536 + scol,      &Vbuf[0][r0 * 64]);
        gl_lds16(Vp + (size_t)(r0 + 8 + srow) * 1536 + scol,  &Vbuf[0][(r0 + 8) * 64]);
    }
    __syncthreads();

    for (int kt = 0; kt < nkt; kt++) {
        const int k0 = kt * 64;
        const int cur = kt & 1;

        // ---- stage tile kt+1 (hides under compute; drained by syncthreads)
        if (kt + 1 < nkt) {
            const int k1 = (kt + 1) * 64;
            const int r0 = wave * 16;
            u16* Kd = &Kbuf[cur ^ 1][0];
            u16* Vd = &Vbuf[cur ^ 1][0];
            gl_lds16(Kp + (size_t)(k1 + r0 + srow) * 64 + scol,       Kd + r0 * 64);
            gl_lds16(Kp + (size_t)(k1 + r0 + 8 + srow) * 64 + scol,   Kd + (r0 + 8) * 64);
            gl_lds16(Vp + (size_t)(r0 + srow) * 1536 + k1 + scol,     Vd + r0 * 64);
            gl_lds16(Vp + (size_t)(r0 + 8 + srow) * 1536 + k1 + scol, Vd + (r0 + 8) * 64);
        }

        // ---- bias for this tile (global, L2/L3-hit; latency overlaps reads)
        float4 bc[4];
        #pragma unroll
        for (int n = 0; n < 4; n++)
            bc[n] = *(const float4*)&bp[k0 + n * 16 + quad * 4];

        // ---- K frags from LDS (swizzled): row = n*16+l16, chunk = ks*4+quad
        const u16* Kb = &Kbuf[cur][0];
        const u16* Vb = &Vbuf[cur][0];
        short8 bk[4][2];
        #pragma unroll
        for (int n = 0; n < 4; n++)
            #pragma unroll
            for (int ks = 0; ks < 2; ks++)
                bk[n][ks] = *(const short8*)
                    &Kb[(n * 16 + l16) * 64 + (((ks * 4 + quad) ^ (l16 & 7)) * 8)];

        // ---- QK^T (swapped): lane q = l16, keys = n*16 + quad*4 + rg
        floatx4 accS[4];
        #pragma unroll
        for (int n = 0; n < 4; n++) {
            accS[n] = zf;
            #pragma unroll
            for (int ks = 0; ks < 2; ks++)
                accS[n] = __builtin_amdgcn_mfma_f32_16x16x32_bf16(
                    bk[n][ks], aq[ks], accS[n], 0, 0, 0);
        }

        // ---- softmax + P pack into swizzled per-wave LDS scratch
        const int qg = q0w + l16;
        const bool domask = (k0 + 63 > q0w + 15 + 512);
        const int lim = qg + 512 - k0;
        char* Pbase = (char*)&Ps[wave][0];
        #pragma unroll
        for (int n = 0; n < 4; n++) {
            const int limn = lim - n * 16 - quad * 4;
            const float* bcn = (const float*)&bc[n];
            float pv[4];
            #pragma unroll
            for (int rg = 0; rg < 4; rg++) {
                float s = fmaf(accS[n][rg], ATTN_SC, bcn[rg]);
                if (domask && rg > limn) s = -1e30f;
                float pe;
                asm("v_exp_f32 %0, %1" : "=v"(pe) : "v"(s));
                lsum += pe;
                pv[rg] = pe;
            }
            unsigned w0, w1;
            asm("v_cvt_pk_bf16_f32 %0, %1, %2" : "=v"(w0) : "v"(pv[0]), "v"(pv[1]));
            asm("v_cvt_pk_bf16_f32 %0, %1, %2" : "=v"(w1) : "v"(pv[2]), "v"(pv[3]));
            // logical byte = l16*128 + n*32 + quad*8 ; phys ^= (l16&7)<<4
            unsigned* pw = (unsigned*)(Pbase +
                (((l16 * 128 + n * 32 + quad * 8)) ^ ((l16 & 7) << 4)));
            pw[0] = w0; pw[1] = w1;
        }

        // ---- PV: A frag = P row l16 (swizzled b128), B frag = V from LDS
        short8 ap[2];
        #pragma unroll
        for (int ks = 0; ks < 2; ks++)
            ap[ks] = *(const short8*)(Pbase +
                (((l16 * 128 + ks * 64 + quad * 16)) ^ ((l16 & 7) << 4)));
        #pragma unroll
        for (int j = 0; j < 4; j++) {
            #pragma unroll
            for (int ks = 0; ks < 2; ks++) {
                short8 bv = *(const short8*)
                    &Vb[(j * 16 + l16) * 64 + (((ks * 4 + quad) ^ (l16 & 7)) * 8)];
                accO[j] = __builtin_amdgcn_mfma_f32_16x16x32_bf16(
                    ap[ks], bv, accO[j], 0, 0, 0);
            }
        }

        __syncthreads();   // drains stage(kt+1) vmcnt + guards buffer reuse
    }

    // lsum quad-reduce: every lane gets full sum for q = l16
    {
        float s = lsum;
        s += __shfl_xor(s, 16, 64);
        s += __shfl_xor(s, 32, 64);
        lsum = s;
    }
    float ltr[4];
    #pragma unroll
    for (int rg = 0; rg < 4; rg++)
        ltr[rg] = __shfl(lsum, quad * 4 + rg, 16);   // sum for q = quad*4+rg

    #pragma unroll
    for (int j = 0; j < 4; j++)
        #pragma unroll
        for (int rg = 0; rg < 4; rg++) {
            const int q = q0w + quad * 4 + rg;
            const int d = j * 16 + l16;
            ctx[((size_t)b * 1024 + q) * 1024 + h * 64 + d] =
                f2bf(accO[j][rg] / ltr[rg]);
        }
}

// ---------------------------------------------------------------------------
// LayerNorm over (partial0 + partial1 + residual query): fp32 -> fp32 d_out
// ---------------------------------------------------------------------------
__global__ __launch_bounds__(256) void ln_kernel(
    const float* __restrict__ x0, const float* __restrict__ x1,
    const float* __restrict__ q,
    const float* __restrict__ gamma, const float* __restrict__ beta,
    float* __restrict__ out)
{
    const int row = blockIdx.x;
    const int tid = threadIdx.x;
    const size_t base = (size_t)row * 1024 + tid * 4;
    float4 a = *(const float4*)&x0[base];
    float4 c = *(const float4*)&x1[base];
    float4 r = *(const float4*)&q[base];
    float4 v;
    v.x = a.x + c.x + r.x; v.y = a.y + c.y + r.y;
    v.z = a.z + c.z + r.z; v.w = a.w + c.w + r.w;
    float s  = v.x + v.y + v.z + v.w;
    float ss = v.x * v.x + v.y * v.y + v.z * v.z + v.w * v.w;
    for (int off = 1; off < 64; off <<= 1) {
        s  += __shfl_xor(s, off, 64);
        ss += __shfl_xor(ss, off, 64);
    }
    __shared__ float sm[8];
    const int wave = tid >> 6, lane = tid & 63;
    if (lane == 0) { sm[wave] = s; sm[4 + wave] = ss; }
    __syncthreads();
    s  = sm[0] + sm[1] + sm[2] + sm[3];
    ss = sm[4] + sm[5] + sm[6] + sm[7];
    const float mu  = s * (1.f / 1024.f);
    const float var = ss * (1.f / 1024.f) - mu * mu;
    const float inv = rsqrtf(var + 1e-5f);
    float* op = out + (size_t)row * 1024;
    const float* ve = &v.x;
    for (int j = 0; j < 4; j++) {
        const int c2 = tid * 4 + j;
        op[c2] = (ve[j] - mu) * inv * gamma[c2] + beta[c2];
    }
}

// ---------------------------------------------------------------------------
extern "C" void kernel_launch(void* const* d_in, const int* in_sizes, int n_in,
                              void* d_out, int out_size, void* d_ws, size_t ws_size,
                              hipStream_t stream)
{
    const float* query     = (const float*)d_in[0];
    const float* key_value = (const float*)d_in[1];
    const float* relative  = (const float*)d_in[2];
    // d_in[3] = mask: analytic (j <= i+512), unused
    const float* Wq = (const float*)d_in[4];
    const float* Wk = (const float*)d_in[5];
    const float* Wv = (const float*)d_in[6];
    const float* Wr = (const float*)d_in[7];
    const float* Wo = (const float*)d_in[8];
    const float* u  = (const float*)d_in[9];
    const float* v  = (const float*)d_in[10];
    const float* gamma = (const float*)d_in[11];
    const float* beta  = (const float*)d_in[12];

    char* wsp = (char*)d_ws;
    auto alloc = [&](size_t bytes) -> char* {
        char* p = wsp; wsp += (bytes + 255) & ~(size_t)255; return p;
    };
    u16*   qb   = (u16*)alloc((size_t)4 * 1024 * 1024 * 2);
    u16*   kvb  = (u16*)alloc((size_t)4 * 1536 * 1024 * 2);
    u16*   relb = (u16*)alloc((size_t)4 * 1536 * 1024 * 2);
    u16*   WqT  = (u16*)alloc((size_t)1024 * 1024 * 2);
    u16*   WkrT = (u16*)alloc((size_t)1024 * 2048 * 2);
    u16*   WvT  = (u16*)alloc((size_t)1024 * 1024 * 2);
    u16*   WoT  = (u16*)alloc((size_t)1024 * 1024 * 2);
    u16*   wuvb = (u16*)alloc((size_t)16 * 2048 * 2);
    u16*   Qh   = (u16*)alloc((size_t)4 * 16 * 1024 * 64 * 2);
    u16*   KRh  = (u16*)alloc((size_t)4 * 16 * 1536 * 64 * 2);
    u16*   Vt   = (u16*)alloc((size_t)4 * 16 * 64 * 1536 * 2);
    float* bias = (float*)alloc((size_t)4 * 16 * 1536 * 4);
    u16*   ctx  = (u16*)alloc((size_t)4 * 1024 * 1024 * 2);
    float* outp = (float*)alloc((size_t)2 * 4 * 1024 * 1024 * 4);  // 2 split-K partials

    const dim3 tb(256);
    cvt3_kernel<<<dim3(3072, 3), tb, 0, stream>>>(
        query, qb, 4 * 1024 * 1024,
        key_value, kvb, 4 * 1536 * 1024,
        relative, relb, 4 * 1536 * 1024);

    transpose5_kernel<<<dim3(16, 16, 5), tb, 0, stream>>>(
        Wq, Wk, Wr, Wv, Wo, WqT, WkrT, WvT, WoT);
    wuv_kernel<<<64, tb, 0, stream>>>(Wk, Wr, u, v, wuvb);

    fused_proj_v2<<<dim3(304), dim3(512), 0, stream>>>(
        qb, kvb, relb, WqT, WkrT, WvT, wuvb, Qh, KRh, Vt, bias);

    attn_kernel<<<dim3(1024), tb, 0, stream>>>(Qh, KRh, Vt, bias, ctx);

    out_gemm<<<dim3(32, 8, 2), tb, 0, stream>>>(ctx, WoT, outp);
    ln_kernel<<<4096, tb, 0, stream>>>(
        outp, outp + (size_t)4 * 1024 * 1024, query, gamma, beta, (float*)d_out);
}

// Round 8
// 287.557 us; speedup vs baseline: 1.1111x; 1.0543x over previous
//
#include <hip/hip_runtime.h>

// Transformer-XL attention, MI355X gfx950.
// All tensors fp32 in global (per reference); internal path bf16 MFMA + fp32 acc.
// B=4 TQ=1024 TK=1536 D=1024 H=16 DV=64, mem=512 causal: j <= i+512.
//
// Round-15: (1) REVERT gemm256_body to round-12 exact (72.5us verified; the
// round-14 m201-sandwich graft regressed to 82us -- extra barrier/phase at
// 1 blk/CU). (2) attn v4: 128 q-rows/block, 8 waves x 512 thr; per-wave code
// identical to v3 but K/V staging + barriers amortized over 2x rows.
// (3) prologue fusion: cvt3+transpose5+wuv in one dispatch (2 fewer launches).

typedef unsigned short u16;
typedef __attribute__((ext_vector_type(8))) short short8;   // 8 bf16 (MFMA A/B frag)
typedef __attribute__((ext_vector_type(4))) float floatx4;  // MFMA C/D frag

// 0.125 * log2(e): folded softmax scale so p = 2^(s*SC + bias*SC) via v_exp_f32
#define ATTN_SC 0.18033688011112042f

__device__ __forceinline__ float bf2f(u16 u) {
    union { unsigned int i; float f; } w; w.i = ((unsigned int)u) << 16; return w.f;
}
__device__ __forceinline__ u16 f2bf(float f) {
    union { unsigned int i; float f; } w; w.f = f;
    unsigned int u = w.i;
    return (u16)((u + 0x7FFFu + ((u >> 16) & 1u)) >> 16);
}

// async global->LDS, 16B per lane; LDS dest = wave-uniform base + lane*16
__device__ __forceinline__ void gl_lds16(const u16* g, u16* lds) {
    __builtin_amdgcn_global_load_lds(
        (const __attribute__((address_space(1))) void*)g,
        (__attribute__((address_space(3))) void*)lds, 16, 0, 0);
}

// ---------------------------------------------------------------------------
// Fused prologue: transpose5 (blocks 0..1279) | wuv (1280..1343) |
// cvt3 (1344..9535: q 2048, kv 3072, rel 3072 blocks).
// ---------------------------------------------------------------------------
__global__ __launch_bounds__(256) void prep_kernel(
    const float* __restrict__ query, u16* __restrict__ qb,
    const float* __restrict__ key_value, u16* __restrict__ kvb,
    const float* __restrict__ relative, u16* __restrict__ relb,
    const float* __restrict__ Wq, const float* __restrict__ Wk,
    const float* __restrict__ Wr, const float* __restrict__ Wv,
    const float* __restrict__ Wo,
    u16* __restrict__ WqT, u16* __restrict__ WkrT,
    u16* __restrict__ WvT, u16* __restrict__ WoT,
    const float* __restrict__ u, const float* __restrict__ v,
    u16* __restrict__ wuvb)
{
    __shared__ u16 ts[64][72];
    const int blk = blockIdx.x;
    const int tid = threadIdx.x;

    if (blk < 1280) {
        // ---- weight transpose + cvt: WT[n][k] = bf16(W[k][n]) ----
        const int z  = blk >> 8;
        const int by = (blk >> 4) & 15;
        const int bx = blk & 15;
        const float* W; u16* WT; int dst_ld, dst_koff;
        switch (z) {
            case 0: W = Wq; WT = WqT;  dst_ld = 1024; dst_koff = 0;    break;
            case 1: W = Wk; WT = WkrT; dst_ld = 2048; dst_koff = 0;    break;
            case 2: W = Wr; WT = WkrT; dst_ld = 2048; dst_koff = 1024; break;
            case 3: W = Wv; WT = WvT;  dst_ld = 1024; dst_koff = 0;    break;
            default:W = Wo; WT = WoT;  dst_ld = 1024; dst_koff = 0;    break;
        }
        const int k0 = bx * 64, n0 = by * 64;
        const int r  = tid >> 2;
        const int c4 = (tid & 3) << 4;
        const float* src = &W[(size_t)(k0 + r) * 1024 + n0 + c4];
        for (int j = 0; j < 16; j += 4) {
            float4 a = *(const float4*)(src + j);
            ts[r][c4 + j + 0] = f2bf(a.x);
            ts[r][c4 + j + 1] = f2bf(a.y);
            ts[r][c4 + j + 2] = f2bf(a.z);
            ts[r][c4 + j + 3] = f2bf(a.w);
        }
        __syncthreads();
        short8 t0, t1;
        for (int j = 0; j < 8; j++) t0[j] = (short)ts[c4 + j][r];
        for (int j = 0; j < 8; j++) t1[j] = (short)ts[c4 + 8 + j][r];
        u16* dst = &WT[(size_t)(n0 + r) * dst_ld + dst_koff + k0 + c4];
        *(short8*)dst       = t0;
        *(short8*)(dst + 8) = t1;
    } else if (blk < 1344) {
        // ---- wuvb[h][k]: k<1024 -> Wk[k][h*64+:]·u ; else Wr·v ----
        int idx = (blk - 1280) * 256 + tid;
        int c = idx >> 4, h = idx & 15;
        float au = 0.f, av = 0.f;
        for (int d = 0; d < 64; d++) {
            au += Wk[(size_t)c * 1024 + h * 64 + d] * u[d];
            av += Wr[(size_t)c * 1024 + h * 64 + d] * v[d];
        }
        wuvb[h * 2048 + c]        = f2bf(au);
        wuvb[h * 2048 + 1024 + c] = f2bf(av);
    } else {
        // ---- fp32 -> bf16 stream cvt for query/key_value/relative ----
        const int c = blk - 1344;
        const float* x; u16* y; int n, bx;
        if (c < 2048)      { x = query;     y = qb;   n = 4 * 1024 * 1024; bx = c; }
        else if (c < 5120) { x = key_value; y = kvb;  n = 6 * 1024 * 1024; bx = c - 2048; }
        else               { x = relative;  y = relb; n = 6 * 1024 * 1024; bx = c - 5120; }
        const int i = (bx * 256 + tid) * 8;
        if (i < n) {
            float4 a = *(const float4*)&x[i];
            float4 bv = *(const float4*)&x[i + 4];
            short8 o;
            o[0] = (short)f2bf(a.x);  o[1] = (short)f2bf(a.y);
            o[2] = (short)f2bf(a.z);  o[3] = (short)f2bf(a.w);
            o[4] = (short)f2bf(bv.x); o[5] = (short)f2bf(bv.y);
            o[6] = (short)f2bf(bv.z); o[7] = (short)f2bf(bv.w);
            *(short8*)&y[i] = o;
        }
    }
}

// ---------------------------------------------------------------------------
// Old 128x128 GEMM tile body (m97-style), kept for out_gemm (EPI 3 only):
// raw fp32 out[m*1024 + col] (split-K partial)
// ---------------------------------------------------------------------------
template <int EPI>
__device__ __forceinline__ void gemm_body(
    const u16* __restrict__ A0, const u16* __restrict__ A1,
    const u16* __restrict__ WT, void* __restrict__ out,
    int Kld, int kbeg, int kend, int Ksplit, int T,
    int bm, int bn, u16* As, u16* Ws)
{
    const int tid = threadIdx.x;
    const int wave = tid >> 6, lane = tid & 63;
    const int wm = wave >> 1, wn = wave & 1;
    const int l16 = lane & 15, quad = lane >> 4;

    floatx4 acc[4][4];
    const floatx4 zf = {0.f, 0.f, 0.f, 0.f};
    for (int i = 0; i < 4; i++) for (int j = 0; j < 4; j++) acc[i][j] = zf;

    const int m_base = bm * 128, n_base = bn * 128;
    const int rl = lane >> 2;          // 0..15 row within 16-row DMA group
    const int cl = (lane & 3) * 8;     // 0,8,16,24 col elems (16B)

    for (int k0 = kbeg; k0 < kend; k0 += 32) {
        const u16* Aptr; int kk;
        if (k0 < Ksplit) { Aptr = A0; kk = k0; } else { Aptr = A1; kk = k0 - Ksplit; }
        __syncthreads();
        for (int half = 0; half < 2; half++) {
            const int r = wave * 32 + half * 16;  // wave-uniform LDS base row
            gl_lds16(Aptr + (size_t)(m_base + r + rl) * 1024 + kk + cl, &As[r * 32]);
            gl_lds16(WT   + (size_t)(n_base + r + rl) * Kld  + k0 + cl, &Ws[r * 32]);
        }
        __syncthreads();

        short8 af[4], bf[4];
        for (int i = 0; i < 4; i++) {
            af[i] = *(const short8*)&As[(wm * 64 + i * 16 + l16) * 32 + quad * 8];
            bf[i] = *(const short8*)&Ws[(wn * 64 + i * 16 + l16) * 32 + quad * 8];
        }
        for (int i = 0; i < 4; i++)
            for (int j = 0; j < 4; j++)
                acc[i][j] = __builtin_amdgcn_mfma_f32_16x16x32_bf16(af[i], bf[j], acc[i][j], 0, 0, 0);
    }

    for (int i = 0; i < 4; i++) {
        for (int rg = 0; rg < 4; rg++) {
            const int m = m_base + wm * 64 + i * 16 + quad * 4 + rg;
            float* op = (float*)out;
            for (int j = 0; j < 4; j++) {
                const int col = n_base + wn * 64 + j * 16 + l16;
                op[(size_t)m * 1024 + col] = acc[i][j][rg];
            }
        }
    }
}

// ---------------------------------------------------------------------------
// 256x256 8-wave deep-pipelined GEMM body (round-12 exact, 72.5us verified).
//   BK=64 = 2 K-halves (ks) of 32 elems. LDS: per matrix a 4-slot ring of
//   [256 rows][32 elems] bf16 (16KB/slot) -> 128KB total.
//   phase(ph): ks=ph>>1, mh=ph&1. B frags read at mh0, held in regs for mh1.
//   Stage stream (1 half/phase): ph0 A-ks1(t+1), ph1 B-ks1(t+1),
//   ph2 A-ks0(t+2), ph3 B-ks0(t+2). Slot of (tile,ks) = (2*tile+ks)&3.
//   Sync: vmcnt(8) before entry barrier (completes t,ks0) + vmcnt(8) at end of
//   ph1 (completes t,ks1); vmcnt(0) only at the last tile. setprio around MFMA.
//   T2 swizzle: 16B chunk ^= (row>>1)&3 on stage-source + ds_read (round-12
//   verified: SQ_LDS_BANK_CONFLICT -> 0).
// ---------------------------------------------------------------------------
__device__ __forceinline__ void stage_half(
    const u16* __restrict__ src, int src_ld, int row_base, int col_base,
    u16* lds_slot, int wave, int lane)
{
    const int r = wave * 16 + (lane >> 2);                        // row in half
    const int c = (((lane & 3) ^ ((lane >> 3) & 3)) << 3);        // pre-swizzled col
    gl_lds16(src + (size_t)(row_base + r) * src_ld + col_base + c,
             lds_slot + wave * 512);
    gl_lds16(src + (size_t)(row_base + 128 + r) * src_ld + col_base + c,
             lds_slot + 4096 + wave * 512);
}

template <int EPI, int T>
__device__ __forceinline__ void gemm256_body(
    const u16* __restrict__ A0, const u16* __restrict__ A1,
    const u16* __restrict__ WT, void* __restrict__ out,
    int Kld, int NT, int KsplitTile, int bm, int bn,
    u16* As, u16* Bs)
{
    const int tid  = threadIdx.x;
    const int wave = tid >> 6, lane = tid & 63;
    const int wm = wave >> 2, wn = wave & 3;       // 2M x 4N wave grid
    const int l16 = lane & 15, quad = lane >> 4;
    const int m_base = bm * 256, n_base = bn * 256;

    floatx4 acc[8][4];
    const floatx4 zf = {0.f, 0.f, 0.f, 0.f};
    #pragma unroll
    for (int i = 0; i < 8; i++)
        #pragma unroll
        for (int j = 0; j < 4; j++) acc[i][j] = zf;

    // --- prologue: 6 halves = tile0 (4) + tile1 ks0 (2) ---
    {
        const u16* sa0 = (0 < KsplitTile) ? A0 : A1;
        stage_half(sa0, 1024, m_base, 0,  As + 0 * 8192, wave, lane); // A t0 ks0
        stage_half(WT,  Kld,  n_base, 0,  Bs + 0 * 8192, wave, lane); // B t0 ks0
        stage_half(sa0, 1024, m_base, 32, As + 1 * 8192, wave, lane); // A t0 ks1
        stage_half(WT,  Kld,  n_base, 32, Bs + 1 * 8192, wave, lane); // B t0 ks1
        const u16* sa1 = (1 < KsplitTile) ? A0 : A1;
        const int  c1  = (1 < KsplitTile) ? 64 : (1 - KsplitTile) * 64;
        stage_half(sa1, 1024, m_base, c1, As + 2 * 8192, wave, lane); // A t1 ks0
        stage_half(WT,  Kld,  n_base, 64, Bs + 2 * 8192, wave, lane); // B t1 ks0
    }

    for (int t = 0; t < NT; ++t) {
        // counted vmcnt before the entry barrier: completes A/B(t,ks0),
        // leaves (t,ks1)+(t+1,ks0) in flight.
        if (t + 1 < NT) asm volatile("s_waitcnt vmcnt(8)" ::: "memory");
        else            asm volatile("s_waitcnt vmcnt(0)" ::: "memory");
        __builtin_amdgcn_s_barrier();

        short8 bfr[4];
        #pragma unroll
        for (int ph = 0; ph < 4; ++ph) {
            if (ph) __builtin_amdgcn_s_barrier();
            const int ks = ph >> 1, mh = ph & 1;

            // ---- stage one half (into a slot freed >=1 barrier ago) ----
            if (ph == 0) {
                if (t + 1 < NT) {
                    const int tt = t + 1;
                    const u16* sa = (tt < KsplitTile) ? A0 : A1;
                    const int cb = (tt < KsplitTile ? tt : tt - KsplitTile) * 64 + 32;
                    stage_half(sa, 1024, m_base, cb, As + ((2 * tt + 1) & 3) * 8192, wave, lane);
                }
            } else if (ph == 1) {
                if (t + 1 < NT)
                    stage_half(WT, Kld, n_base, (t + 1) * 64 + 32,
                               Bs + ((2 * (t + 1) + 1) & 3) * 8192, wave, lane);
            } else if (ph == 2) {
                if (t + 2 < NT) {
                    const int tt = t + 2;
                    const u16* sa = (tt < KsplitTile) ? A0 : A1;
                    const int cb = (tt < KsplitTile ? tt : tt - KsplitTile) * 64;
                    stage_half(sa, 1024, m_base, cb, As + ((2 * tt) & 3) * 8192, wave, lane);
                }
            } else {
                if (t + 2 < NT)
                    stage_half(WT, Kld, n_base, (t + 2) * 64,
                               Bs + ((2 * (t + 2)) & 3) * 8192, wave, lane);
            }

            // ---- ds_read fragments (swizzled: chunk ^= (row>>1)&3) ----
            const u16* Aslot = As + ((2 * t + ks) & 3) * 8192;
            const u16* Bslot = Bs + ((2 * t + ks) & 3) * 8192;
            if (mh == 0) {
                #pragma unroll
                for (int nj = 0; nj < 4; ++nj) {
                    const int row = wn * 64 + nj * 16 + l16;
                    bfr[nj] = *(const short8*)&Bslot[row * 32 + (((quad ^ (row >> 1)) & 3) << 3)];
                }
            }
            short8 af[4];
            #pragma unroll
            for (int mi = 0; mi < 4; ++mi) {
                const int row = wm * 128 + mh * 64 + mi * 16 + l16;
                af[mi] = *(const short8*)&Aslot[row * 32 + (((quad ^ (row >> 1)) & 3) << 3)];
            }

            __builtin_amdgcn_s_setprio(1);
            #pragma unroll
            for (int mi = 0; mi < 4; ++mi)
                #pragma unroll
                for (int nj = 0; nj < 4; ++nj)
                    acc[mh * 4 + mi][nj] = __builtin_amdgcn_mfma_f32_16x16x32_bf16(
                        af[mi], bfr[nj], acc[mh * 4 + mi][nj], 0, 0, 0);
            __builtin_amdgcn_s_setprio(0);

            // counted vmcnt before ph2's barrier: completes A/B(t,ks1),
            // leaves (t+1,ks0)+(t+1,ks1) in flight.
            if (ph == 1 && t + 1 < NT)
                asm volatile("s_waitcnt vmcnt(8)" ::: "memory");
        }
    }

    // ---- epilogue ----
    u16* op = (u16*)out;
    #pragma unroll
    for (int mi = 0; mi < 8; ++mi) {
        #pragma unroll
        for (int rg = 0; rg < 4; ++rg) {
            const int m = m_base + wm * 128 + mi * 16 + quad * 4 + rg;
            const int b = m / T, tk = m % T;   // T is compile-time -> magic mul
            #pragma unroll
            for (int nj = 0; nj < 4; ++nj) {
                const int col = n_base + wn * 64 + nj * 16 + l16;
                const int h = col >> 6, d = col & 63;
                if (EPI == 0) {
                    op[(((size_t)(b * 16 + h) * T + tk) << 6) + d] = f2bf(acc[mi][nj][rg]);
                } else {  // EPI == 2: head-transposed V^T
                    op[((size_t)(b * 16 + h) * 64 + d) * 1536 + tk] = f2bf(acc[mi][nj][rg]);
                }
            }
        }
    }
}

// ---------------------------------------------------------------------------
// bias body, 8-wave version: [6144,2048]@[2048,16] skinny MFMA, 16 tokens/wave
// Output prescaled by ATTN_SC (softmax scale+log2e fold for attn's 1-FMA score).
// ---------------------------------------------------------------------------
__device__ __forceinline__ void bias_body8(
    const u16* __restrict__ kvb, const u16* __restrict__ relb,
    const u16* __restrict__ wuvb, float* __restrict__ bias, int bblk)
{
    const int tid = threadIdx.x;
    const int wave = tid >> 6, lane = tid & 63;
    const int l16 = lane & 15, quad = lane >> 4;
    const int tBase = bblk * 128 + wave * 16;

    floatx4 acc = {0.f, 0.f, 0.f, 0.f};
    const u16* arow_kv  = kvb  + (size_t)(tBase + l16) * 1024;
    const u16* arow_rel = relb + (size_t)(tBase + l16) * 1024;
    const u16* brow     = wuvb + (size_t)l16 * 2048;

    for (int ks = 0; ks < 64; ks++) {
        const int k0 = ks * 32;
        const u16* ap = (k0 < 1024) ? (arow_kv + k0) : (arow_rel + k0 - 1024);
        short8 af = *(const short8*)(ap + quad * 8);
        short8 bf = *(const short8*)(brow + k0 + quad * 8);
        acc = __builtin_amdgcn_mfma_f32_16x16x32_bf16(af, bf, acc, 0, 0, 0);
    }
    for (int rg = 0; rg < 4; rg++) {
        const int tg = tBase + quad * 4 + rg;
        const int b = tg / 1536, t = tg % 1536;
        bias[((size_t)b * 16 + l16) * 1536 + t] = acc[rg] * ATTN_SC;
    }
}

// ---------------------------------------------------------------------------
// Fused projection dispatch v2: 304 blocks x 512 threads
//   (KR 96 | V 96 | Q 64 | bias 48), heavy (K=2048) blocks first.
// ---------------------------------------------------------------------------
__global__ __launch_bounds__(512) void fused_proj_v2(
    const u16* __restrict__ qb, const u16* __restrict__ kvb,
    const u16* __restrict__ relb,
    const u16* __restrict__ WqT, const u16* __restrict__ WkrT,
    const u16* __restrict__ WvT, const u16* __restrict__ wuvb,
    u16* __restrict__ Qh, u16* __restrict__ KRh, u16* __restrict__ Vt,
    float* __restrict__ bias)
{
    __shared__ __align__(128) u16 As[4 * 256 * 32];  // 64KB: 4-slot A ring
    __shared__ __align__(128) u16 Bs[4 * 256 * 32];  // 64KB: 4-slot B ring
    const int blk = blockIdx.x;
    if (blk < 96) {
        // KR: M=6144 K=2048 (kvb tiles 0..15, relb 16..31), T=1536
        gemm256_body<0, 1536>(kvb, relb, WkrT, KRh, 2048, 32, 16,
                              blk % 24, blk / 24, As, Bs);
    } else if (blk < 192) {
        const int i = blk - 96;   // V: M=6144 K=1024, head-transposed out
        gemm256_body<2, 1536>(kvb, kvb, WvT, Vt, 1024, 16, 99,
                              i % 24, i / 24, As, Bs);
    } else if (blk < 256) {
        const int i = blk - 192;  // Q: M=4096 K=1024, T=1024
        gemm256_body<0, 1024>(qb, qb, WqT, Qh, 1024, 16, 99,
                              i % 16, i / 16, As, Bs);
    } else {
        bias_body8(kvb, relb, wuvb, bias, blk - 256);
    }
}

// ---------------------------------------------------------------------------
// Output GEMM, split-K=2 (grid (32,8,2) = 512 blocks = 2/CU): raw fp32
// partials to outp + z*4M; LayerNorm sums partials + residual.
// ---------------------------------------------------------------------------
__global__ __launch_bounds__(256) void out_gemm(
    const u16* __restrict__ ctx, const u16* __restrict__ WoT,
    float* __restrict__ outp)
{
    __shared__ u16 smem[2 * 128 * 32];
    const int z = blockIdx.z;
    gemm_body<3>(ctx, nullptr, WoT,
                 outp + (size_t)z * 4 * 1024 * 1024, 1024,
                 z * 512, z * 512 + 512, 1024, 1024,
                 blockIdx.x, blockIdx.y, smem, smem + 128 * 32);
}

// ---------------------------------------------------------------------------
// Flash attention v4 (round-15): 128 q-rows/block, 8 waves x 512 threads.
// Per-wave code identical to v3 (16 q-rows, full 64-key tile); K/V staging
// (2 gl_lds/wave: 8 K rows + 8 V rows), barriers, and HBM K/V fetches are
// amortized over 2x q-rows vs v3. 512 blocks (8 qblk x 64 hb), LDS 48KB.
// Exact-exp softmax; swapped QK^T; XOR swizzle chunk^=(row&7) on K/V/P.
// ---------------------------------------------------------------------------
__global__ __launch_bounds__(512, 4) void attn_kernel(
    const u16* __restrict__ Qh,   // [B][H][1024][64]
    const u16* __restrict__ KRh,  // [B][H][1536][64]
    const u16* __restrict__ Vt,   // [B][H][64][1536]
    const float* __restrict__ bias, // [B][H][1536], prescaled by ATTN_SC
    u16* __restrict__ ctx)        // [B][1024][1024] token-major
{
    const int blk  = blockIdx.x;
    const int hb   = blk & 63;          // XCD-residue swizzle on (b,h)
    const int qblk = blk >> 6;          // 0..7, 128 q-rows per block
    const int b = hb >> 4, h = hb & 15;
    const int tid = threadIdx.x;
    const int wave = tid >> 6, lane = tid & 63;   // wave 0..7
    const int l16 = lane & 15, quad = lane >> 4;
    const int q0w = qblk * 128 + wave * 16;   // this wave's 16 q-rows

    const u16* Qp = Qh  + (size_t)hb * 1024 * 64;
    const u16* Kp = KRh + (size_t)hb * 1536 * 64;
    const u16* Vp = Vt  + (size_t)hb * 64 * 1536;
    const float* bp = bias + (size_t)hb * 1536;

    __shared__ __align__(128) u16 Kbuf[2][64 * 64];  // 16KB  [key][d] swz
    __shared__ __align__(128) u16 Vbuf[2][64 * 64];  // 16KB  [d][key] swz
    __shared__ __align__(128) u16 Ps[8][16 * 64];    // 16KB per-wave P, swz

    // stage: each wave owns 8 K rows + 8 V rows (1 gl_lds each = 8 rows).
    // linear LDS dest; source chunk pre-swizzled: phys(row,chunk) holds
    // global (row, chunk ^ (row&7)); row&7 == lane>>3 within each 8-row grp.
    const int srow = lane >> 3;                   // 0..7
    const int scol = ((lane & 7) ^ srow) * 8;     // swizzled source col (elems)

    const floatx4 zf = {0.f, 0.f, 0.f, 0.f};
    floatx4 accO[4];
    float lsum = 0.f;
    #pragma unroll
    for (int j = 0; j < 4; j++) accO[j] = zf;

    short8 aq[2];
    #pragma unroll
    for (int ks = 0; ks < 2; ks++)
        aq[ks] = *(const short8*)
            &Qp[(size_t)(q0w + l16) * 64 + ks * 32 + quad * 8];

    const int nkt = 2 * qblk + 10;   // tiles cover keys 0 .. qblk*128+127+512

    // prologue: stage tile 0 into buf 0
    {
        const int r0 = wave * 8;
        gl_lds16(Kp + (size_t)(r0 + srow) * 64 + scol,   &Kbuf[0][r0 * 64]);
        gl_lds16(Vp + (size_t)(r0 + srow) * 1536 + scol, &Vbuf[0][r0 * 64]);
    }
    __syncthreads();

    for (int kt = 0; kt < nkt; kt++) {
        const int k0 = kt * 64;
        const int cur = kt & 1;

        // ---- stage tile kt+1 (hides under compute; drained by syncthreads)
        if (kt + 1 < nkt) {
            const int k1 = (kt + 1) * 64;
            const int r0 = wave * 8;
            gl_lds16(Kp + (size_t)(k1 + r0 + srow) * 64 + scol,
                     &Kbuf[cur ^ 1][r0 * 64]);
            gl_lds16(Vp + (size_t)(r0 + srow) * 1536 + k1 + scol,
                     &Vbuf[cur ^ 1][r0 * 64]);
        }

        // ---- bias for this tile (global, L2/L3-hit; latency overlaps reads)
        float4 bc[4];
        #pragma unroll
        for (int n = 0; n < 4; n++)
            bc[n] = *(const float4*)&bp[k0 + n * 16 + quad * 4];

        // ---- K frags from LDS (swizzled): row = n*16+l16, chunk = ks*4+quad
        const u16* Kb = &Kbuf[cur][0];
        const u16* Vb = &Vbuf[cur][0];
        short8 bk[4][2];
        #pragma unroll
        for (int n = 0; n < 4; n++)
            #pragma unroll
            for (int ks = 0; ks < 2; ks++)
                bk[n][ks] = *(const short8*)
                    &Kb[(n * 16 + l16) * 64 + (((ks * 4 + quad) ^ (l16 & 7)) * 8)];

        // ---- QK^T (swapped): lane q = l16, keys = n*16 + quad*4 + rg
        floatx4 accS[4];
        #pragma unroll
        for (int n = 0; n < 4; n++) {
            accS[n] = zf;
            #pragma unroll
            for (int ks = 0; ks < 2; ks++)
                accS[n] = __builtin_amdgcn_mfma_f32_16x16x32_bf16(
                    bk[n][ks], aq[ks], accS[n], 0, 0, 0);
        }

        // ---- softmax + P pack into swizzled per-wave LDS scratch
        const int qg = q0w + l16;
        const bool domask = (k0 + 63 > q0w + 15 + 512);
        const int lim = qg + 512 - k0;
        char* Pbase = (char*)&Ps[wave][0];
        #pragma unroll
        for (int n = 0; n < 4; n++) {
            const int limn = lim - n * 16 - quad * 4;
            const float* bcn = (const float*)&bc[n];
            float pv[4];
            #pragma unroll
            for (int rg = 0; rg < 4; rg++) {
                float s = fmaf(accS[n][rg], ATTN_SC, bcn[rg]);
                if (domask && rg > limn) s = -1e30f;
                float pe;
                asm("v_exp_f32 %0, %1" : "=v"(pe) : "v"(s));
                lsum += pe;
                pv[rg] = pe;
            }
            unsigned w0, w1;
            asm("v_cvt_pk_bf16_f32 %0, %1, %2" : "=v"(w0) : "v"(pv[0]), "v"(pv[1]));
            asm("v_cvt_pk_bf16_f32 %0, %1, %2" : "=v"(w1) : "v"(pv[2]), "v"(pv[3]));
            // logical byte = l16*128 + n*32 + quad*8 ; phys ^= (l16&7)<<4
            unsigned* pw = (unsigned*)(Pbase +
                (((l16 * 128 + n * 32 + quad * 8)) ^ ((l16 & 7) << 4)));
            pw[0] = w0; pw[1] = w1;
        }

        // ---- PV: A frag = P row l16 (swizzled b128), B frag = V from LDS
        short8 ap[2];
        #pragma unroll
        for (int ks = 0; ks < 2; ks++)
            ap[ks] = *(const short8*)(Pbase +
                (((l16 * 128 + ks * 64 + quad * 16)) ^ ((l16 & 7) << 4)));
        #pragma unroll
        for (int j = 0; j < 4; j++) {
            #pragma unroll
            for (int ks = 0; ks < 2; ks++) {
                short8 bv = *(const short8*)
                    &Vb[(j * 16 + l16) * 64 + (((ks * 4 + quad) ^ (l16 & 7)) * 8)];
                accO[j] = __builtin_amdgcn_mfma_f32_16x16x32_bf16(
                    ap[ks], bv, accO[j], 0, 0, 0);
            }
        }

        __syncthreads();   // drains stage(kt+1) vmcnt + guards buffer reuse
    }

    // lsum quad-reduce: every lane gets full sum for q = l16
    {
        float s = lsum;
        s += __shfl_xor(s, 16, 64);
        s += __shfl_xor(s, 32, 64);
        lsum = s;
    }
    float ltr[4];
    #pragma unroll
    for (int rg = 0; rg < 4; rg++)
        ltr[rg] = __shfl(lsum, quad * 4 + rg, 16);   // sum for q = quad*4+rg

    #pragma unroll
    for (int j = 0; j < 4; j++)
        #pragma unroll
        for (int rg = 0; rg < 4; rg++) {
            const int q = q0w + quad * 4 + rg;
            const int d = j * 16 + l16;
            ctx[((size_t)b * 1024 + q) * 1024 + h * 64 + d] =
                f2bf(accO[j][rg] / ltr[rg]);
        }
}

// ---------------------------------------------------------------------------
// LayerNorm over (partial0 + partial1 + residual query): fp32 -> fp32 d_out
// ---------------------------------------------------------------------------
__global__ __launch_bounds__(256) void ln_kernel(
    const float* __restrict__ x0, const float* __restrict__ x1,
    const float* __restrict__ q,
    const float* __restrict__ gamma, const float* __restrict__ beta,
    float* __restrict__ out)
{
    const int row = blockIdx.x;
    const int tid = threadIdx.x;
    const size_t base = (size_t)row * 1024 + tid * 4;
    float4 a = *(const float4*)&x0[base];
    float4 c = *(const float4*)&x1[base];
    float4 r = *(const float4*)&q[base];
    float4 v;
    v.x = a.x + c.x + r.x; v.y = a.y + c.y + r.y;
    v.z = a.z + c.z + r.z; v.w = a.w + c.w + r.w;
    float s  = v.x + v.y + v.z + v.w;
    float ss = v.x * v.x + v.y * v.y + v.z * v.z + v.w * v.w;
    for (int off = 1; off < 64; off <<= 1) {
        s  += __shfl_xor(s, off, 64);
        ss += __shfl_xor(ss, off, 64);
    }
    __shared__ float sm[8];
    const int wave = tid >> 6, lane = tid & 63;
    if (lane == 0) { sm[wave] = s; sm[4 + wave] = ss; }
    __syncthreads();
    s  = sm[0] + sm[1] + sm[2] + sm[3];
    ss = sm[4] + sm[5] + sm[6] + sm[7];
    const float mu  = s * (1.f / 1024.f);
    const float var = ss * (1.f / 1024.f) - mu * mu;
    const float inv = rsqrtf(var + 1e-5f);
    float* op = out + (size_t)row * 1024;
    const float* ve = &v.x;
    for (int j = 0; j < 4; j++) {
        const int c2 = tid * 4 + j;
        op[c2] = (ve[j] - mu) * inv * gamma[c2] + beta[c2];
    }
}

// ---------------------------------------------------------------------------
extern "C" void kernel_launch(void* const* d_in, const int* in_sizes, int n_in,
                              void* d_out, int out_size, void* d_ws, size_t ws_size,
                              hipStream_t stream)
{
    const float* query     = (const float*)d_in[0];
    const float* key_value = (const float*)d_in[1];
    const float* relative  = (const float*)d_in[2];
    // d_in[3] = mask: analytic (j <= i+512), unused
    const float* Wq = (const float*)d_in[4];
    const float* Wk = (const float*)d_in[5];
    const float* Wv = (const float*)d_in[6];
    const float* Wr = (const float*)d_in[7];
    const float* Wo = (const float*)d_in[8];
    const float* u  = (const float*)d_in[9];
    const float* v  = (const float*)d_in[10];
    const float* gamma = (const float*)d_in[11];
    const float* beta  = (const float*)d_in[12];

    char* wsp = (char*)d_ws;
    auto alloc = [&](size_t bytes) -> char* {
        char* p = wsp; wsp += (bytes + 255) & ~(size_t)255; return p;
    };
    u16*   qb   = (u16*)alloc((size_t)4 * 1024 * 1024 * 2);
    u16*   kvb  = (u16*)alloc((size_t)4 * 1536 * 1024 * 2);
    u16*   relb = (u16*)alloc((size_t)4 * 1536 * 1024 * 2);
    u16*   WqT  = (u16*)alloc((size_t)1024 * 1024 * 2);
    u16*   WkrT = (u16*)alloc((size_t)1024 * 2048 * 2);
    u16*   WvT  = (u16*)alloc((size_t)1024 * 1024 * 2);
    u16*   WoT  = (u16*)alloc((size_t)1024 * 1024 * 2);
    u16*   wuvb = (u16*)alloc((size_t)16 * 2048 * 2);
    u16*   Qh   = (u16*)alloc((size_t)4 * 16 * 1024 * 64 * 2);
    u16*   KRh  = (u16*)alloc((size_t)4 * 16 * 1536 * 64 * 2);
    u16*   Vt   = (u16*)alloc((size_t)4 * 16 * 64 * 1536 * 2);
    float* bias = (float*)alloc((size_t)4 * 16 * 1536 * 4);
    u16*   ctx  = (u16*)alloc((size_t)4 * 1024 * 1024 * 2);
    float* outp = (float*)alloc((size_t)2 * 4 * 1024 * 1024 * 4);  // 2 split-K partials

    const dim3 tb(256);
    prep_kernel<<<dim3(9536), tb, 0, stream>>>(
        query, qb, key_value, kvb, relative, relb,
        Wq, Wk, Wr, Wv, Wo, WqT, WkrT, WvT, WoT, u, v, wuvb);

    fused_proj_v2<<<dim3(304), dim3(512), 0, stream>>>(
        qb, kvb, relb, WqT, WkrT, WvT, wuvb, Qh, KRh, Vt, bias);

    attn_kernel<<<dim3(512), dim3(512), 0, stream>>>(Qh, KRh, Vt, bias, ctx);

    out_gemm<<<dim3(32, 8, 2), tb, 0, stream>>>(ctx, WoT, outp);
    ln_kernel<<<4096, tb, 0, stream>>>(
        outp, outp + (size_t)4 * 1024 * 1024, query, gamma, beta, (float*)d_out);
}

// Round 9
// 286.153 us; speedup vs baseline: 1.1166x; 1.0049x over previous
//
#include <hip/hip_runtime.h>

// Transformer-XL attention, MI355X gfx950.
// All tensors fp32 in global (per reference); internal path bf16 MFMA + fp32 acc.
// B=4 TQ=1024 TK=1536 D=1024 H=16 DV=64, mem=512 causal: j <= i+512.
//
// Round-16: attn v5. v4's per-tile __syncthreads = vmcnt(0) drain -> each
// staged tile force-completed within ONE compute phase. v5: 3-slot K/V ring,
// counted vmcnt(2) + raw s_barrier per tile (T3/T4): each stage gets 2 compute
// phases to land; never drain to 0 in the main loop. LDS 48->64KB (2 blk/CU).
// Heavy-first dispatch: qblk = 7 - blk>>6 (24-tile blocks start first).
// fused_proj frozen at round-12 state (72.5us, 3 schedule attempts all lost).

typedef unsigned short u16;
typedef __attribute__((ext_vector_type(8))) short short8;   // 8 bf16 (MFMA A/B frag)
typedef __attribute__((ext_vector_type(4))) float floatx4;  // MFMA C/D frag

// 0.125 * log2(e): folded softmax scale so p = 2^(s*SC + bias*SC) via v_exp_f32
#define ATTN_SC 0.18033688011112042f

__device__ __forceinline__ float bf2f(u16 u) {
    union { unsigned int i; float f; } w; w.i = ((unsigned int)u) << 16; return w.f;
}
__device__ __forceinline__ u16 f2bf(float f) {
    union { unsigned int i; float f; } w; w.f = f;
    unsigned int u = w.i;
    return (u16)((u + 0x7FFFu + ((u >> 16) & 1u)) >> 16);
}

// async global->LDS, 16B per lane; LDS dest = wave-uniform base + lane*16
__device__ __forceinline__ void gl_lds16(const u16* g, u16* lds) {
    __builtin_amdgcn_global_load_lds(
        (const __attribute__((address_space(1))) void*)g,
        (__attribute__((address_space(3))) void*)lds, 16, 0, 0);
}

// ---------------------------------------------------------------------------
// Fused prologue: transpose5 (blocks 0..1279) | wuv (1280..1343) |
// cvt3 (1344..9535: q 2048, kv 3072, rel 3072 blocks).
// ---------------------------------------------------------------------------
__global__ __launch_bounds__(256) void prep_kernel(
    const float* __restrict__ query, u16* __restrict__ qb,
    const float* __restrict__ key_value, u16* __restrict__ kvb,
    const float* __restrict__ relative, u16* __restrict__ relb,
    const float* __restrict__ Wq, const float* __restrict__ Wk,
    const float* __restrict__ Wr, const float* __restrict__ Wv,
    const float* __restrict__ Wo,
    u16* __restrict__ WqT, u16* __restrict__ WkrT,
    u16* __restrict__ WvT, u16* __restrict__ WoT,
    const float* __restrict__ u, const float* __restrict__ v,
    u16* __restrict__ wuvb)
{
    __shared__ u16 ts[64][72];
    const int blk = blockIdx.x;
    const int tid = threadIdx.x;

    if (blk < 1280) {
        // ---- weight transpose + cvt: WT[n][k] = bf16(W[k][n]) ----
        const int z  = blk >> 8;
        const int by = (blk >> 4) & 15;
        const int bx = blk & 15;
        const float* W; u16* WT; int dst_ld, dst_koff;
        switch (z) {
            case 0: W = Wq; WT = WqT;  dst_ld = 1024; dst_koff = 0;    break;
            case 1: W = Wk; WT = WkrT; dst_ld = 2048; dst_koff = 0;    break;
            case 2: W = Wr; WT = WkrT; dst_ld = 2048; dst_koff = 1024; break;
            case 3: W = Wv; WT = WvT;  dst_ld = 1024; dst_koff = 0;    break;
            default:W = Wo; WT = WoT;  dst_ld = 1024; dst_koff = 0;    break;
        }
        const int k0 = bx * 64, n0 = by * 64;
        const int r  = tid >> 2;
        const int c4 = (tid & 3) << 4;
        const float* src = &W[(size_t)(k0 + r) * 1024 + n0 + c4];
        for (int j = 0; j < 16; j += 4) {
            float4 a = *(const float4*)(src + j);
            ts[r][c4 + j + 0] = f2bf(a.x);
            ts[r][c4 + j + 1] = f2bf(a.y);
            ts[r][c4 + j + 2] = f2bf(a.z);
            ts[r][c4 + j + 3] = f2bf(a.w);
        }
        __syncthreads();
        short8 t0, t1;
        for (int j = 0; j < 8; j++) t0[j] = (short)ts[c4 + j][r];
        for (int j = 0; j < 8; j++) t1[j] = (short)ts[c4 + 8 + j][r];
        u16* dst = &WT[(size_t)(n0 + r) * dst_ld + dst_koff + k0 + c4];
        *(short8*)dst       = t0;
        *(short8*)(dst + 8) = t1;
    } else if (blk < 1344) {
        // ---- wuvb[h][k]: k<1024 -> Wk[k][h*64+:]·u ; else Wr·v ----
        int idx = (blk - 1280) * 256 + tid;
        int c = idx >> 4, h = idx & 15;
        float au = 0.f, av = 0.f;
        for (int d = 0; d < 64; d++) {
            au += Wk[(size_t)c * 1024 + h * 64 + d] * u[d];
            av += Wr[(size_t)c * 1024 + h * 64 + d] * v[d];
        }
        wuvb[h * 2048 + c]        = f2bf(au);
        wuvb[h * 2048 + 1024 + c] = f2bf(av);
    } else {
        // ---- fp32 -> bf16 stream cvt for query/key_value/relative ----
        const int c = blk - 1344;
        const float* x; u16* y; int n, bx;
        if (c < 2048)      { x = query;     y = qb;   n = 4 * 1024 * 1024; bx = c; }
        else if (c < 5120) { x = key_value; y = kvb;  n = 6 * 1024 * 1024; bx = c - 2048; }
        else               { x = relative;  y = relb; n = 6 * 1024 * 1024; bx = c - 5120; }
        const int i = (bx * 256 + tid) * 8;
        if (i < n) {
            float4 a = *(const float4*)&x[i];
            float4 bv = *(const float4*)&x[i + 4];
            short8 o;
            o[0] = (short)f2bf(a.x);  o[1] = (short)f2bf(a.y);
            o[2] = (short)f2bf(a.z);  o[3] = (short)f2bf(a.w);
            o[4] = (short)f2bf(bv.x); o[5] = (short)f2bf(bv.y);
            o[6] = (short)f2bf(bv.z); o[7] = (short)f2bf(bv.w);
            *(short8*)&y[i] = o;
        }
    }
}

// ---------------------------------------------------------------------------
// Old 128x128 GEMM tile body (m97-style), kept for out_gemm (EPI 3 only):
// raw fp32 out[m*1024 + col] (split-K partial)
// ---------------------------------------------------------------------------
template <int EPI>
__device__ __forceinline__ void gemm_body(
    const u16* __restrict__ A0, const u16* __restrict__ A1,
    const u16* __restrict__ WT, void* __restrict__ out,
    int Kld, int kbeg, int kend, int Ksplit, int T,
    int bm, int bn, u16* As, u16* Ws)
{
    const int tid = threadIdx.x;
    const int wave = tid >> 6, lane = tid & 63;
    const int wm = wave >> 1, wn = wave & 1;
    const int l16 = lane & 15, quad = lane >> 4;

    floatx4 acc[4][4];
    const floatx4 zf = {0.f, 0.f, 0.f, 0.f};
    for (int i = 0; i < 4; i++) for (int j = 0; j < 4; j++) acc[i][j] = zf;

    const int m_base = bm * 128, n_base = bn * 128;
    const int rl = lane >> 2;          // 0..15 row within 16-row DMA group
    const int cl = (lane & 3) * 8;     // 0,8,16,24 col elems (16B)

    for (int k0 = kbeg; k0 < kend; k0 += 32) {
        const u16* Aptr; int kk;
        if (k0 < Ksplit) { Aptr = A0; kk = k0; } else { Aptr = A1; kk = k0 - Ksplit; }
        __syncthreads();
        for (int half = 0; half < 2; half++) {
            const int r = wave * 32 + half * 16;  // wave-uniform LDS base row
            gl_lds16(Aptr + (size_t)(m_base + r + rl) * 1024 + kk + cl, &As[r * 32]);
            gl_lds16(WT   + (size_t)(n_base + r + rl) * Kld  + k0 + cl, &Ws[r * 32]);
        }
        __syncthreads();

        short8 af[4], bf[4];
        for (int i = 0; i < 4; i++) {
            af[i] = *(const short8*)&As[(wm * 64 + i * 16 + l16) * 32 + quad * 8];
            bf[i] = *(const short8*)&Ws[(wn * 64 + i * 16 + l16) * 32 + quad * 8];
        }
        for (int i = 0; i < 4; i++)
            for (int j = 0; j < 4; j++)
                acc[i][j] = __builtin_amdgcn_mfma_f32_16x16x32_bf16(af[i], bf[j], acc[i][j], 0, 0, 0);
    }

    for (int i = 0; i < 4; i++) {
        for (int rg = 0; rg < 4; rg++) {
            const int m = m_base + wm * 64 + i * 16 + quad * 4 + rg;
            float* op = (float*)out;
            for (int j = 0; j < 4; j++) {
                const int col = n_base + wn * 64 + j * 16 + l16;
                op[(size_t)m * 1024 + col] = acc[i][j][rg];
            }
        }
    }
}

// ---------------------------------------------------------------------------
// 256x256 8-wave deep-pipelined GEMM body (round-12 exact, 72.5us verified).
//   BK=64 = 2 K-halves (ks) of 32 elems. LDS: per matrix a 4-slot ring of
//   [256 rows][32 elems] bf16 (16KB/slot) -> 128KB total.
//   phase(ph): ks=ph>>1, mh=ph&1. B frags read at mh0, held in regs for mh1.
//   Stage stream (1 half/phase): ph0 A-ks1(t+1), ph1 B-ks1(t+1),
//   ph2 A-ks0(t+2), ph3 B-ks0(t+2). Slot of (tile,ks) = (2*tile+ks)&3.
//   Sync: vmcnt(8) before entry barrier (completes t,ks0) + vmcnt(8) at end of
//   ph1 (completes t,ks1); vmcnt(0) only at the last tile. setprio around MFMA.
//   T2 swizzle: 16B chunk ^= (row>>1)&3 on stage-source + ds_read (round-12
//   verified: SQ_LDS_BANK_CONFLICT -> 0).
// ---------------------------------------------------------------------------
__device__ __forceinline__ void stage_half(
    const u16* __restrict__ src, int src_ld, int row_base, int col_base,
    u16* lds_slot, int wave, int lane)
{
    const int r = wave * 16 + (lane >> 2);                        // row in half
    const int c = (((lane & 3) ^ ((lane >> 3) & 3)) << 3);        // pre-swizzled col
    gl_lds16(src + (size_t)(row_base + r) * src_ld + col_base + c,
             lds_slot + wave * 512);
    gl_lds16(src + (size_t)(row_base + 128 + r) * src_ld + col_base + c,
             lds_slot + 4096 + wave * 512);
}

template <int EPI, int T>
__device__ __forceinline__ void gemm256_body(
    const u16* __restrict__ A0, const u16* __restrict__ A1,
    const u16* __restrict__ WT, void* __restrict__ out,
    int Kld, int NT, int KsplitTile, int bm, int bn,
    u16* As, u16* Bs)
{
    const int tid  = threadIdx.x;
    const int wave = tid >> 6, lane = tid & 63;
    const int wm = wave >> 2, wn = wave & 3;       // 2M x 4N wave grid
    const int l16 = lane & 15, quad = lane >> 4;
    const int m_base = bm * 256, n_base = bn * 256;

    floatx4 acc[8][4];
    const floatx4 zf = {0.f, 0.f, 0.f, 0.f};
    #pragma unroll
    for (int i = 0; i < 8; i++)
        #pragma unroll
        for (int j = 0; j < 4; j++) acc[i][j] = zf;

    // --- prologue: 6 halves = tile0 (4) + tile1 ks0 (2) ---
    {
        const u16* sa0 = (0 < KsplitTile) ? A0 : A1;
        stage_half(sa0, 1024, m_base, 0,  As + 0 * 8192, wave, lane); // A t0 ks0
        stage_half(WT,  Kld,  n_base, 0,  Bs + 0 * 8192, wave, lane); // B t0 ks0
        stage_half(sa0, 1024, m_base, 32, As + 1 * 8192, wave, lane); // A t0 ks1
        stage_half(WT,  Kld,  n_base, 32, Bs + 1 * 8192, wave, lane); // B t0 ks1
        const u16* sa1 = (1 < KsplitTile) ? A0 : A1;
        const int  c1  = (1 < KsplitTile) ? 64 : (1 - KsplitTile) * 64;
        stage_half(sa1, 1024, m_base, c1, As + 2 * 8192, wave, lane); // A t1 ks0
        stage_half(WT,  Kld,  n_base, 64, Bs + 2 * 8192, wave, lane); // B t1 ks0
    }

    for (int t = 0; t < NT; ++t) {
        // counted vmcnt before the entry barrier: completes A/B(t,ks0),
        // leaves (t,ks1)+(t+1,ks0) in flight.
        if (t + 1 < NT) asm volatile("s_waitcnt vmcnt(8)" ::: "memory");
        else            asm volatile("s_waitcnt vmcnt(0)" ::: "memory");
        __builtin_amdgcn_s_barrier();

        short8 bfr[4];
        #pragma unroll
        for (int ph = 0; ph < 4; ++ph) {
            if (ph) __builtin_amdgcn_s_barrier();
            const int ks = ph >> 1, mh = ph & 1;

            // ---- stage one half (into a slot freed >=1 barrier ago) ----
            if (ph == 0) {
                if (t + 1 < NT) {
                    const int tt = t + 1;
                    const u16* sa = (tt < KsplitTile) ? A0 : A1;
                    const int cb = (tt < KsplitTile ? tt : tt - KsplitTile) * 64 + 32;
                    stage_half(sa, 1024, m_base, cb, As + ((2 * tt + 1) & 3) * 8192, wave, lane);
                }
            } else if (ph == 1) {
                if (t + 1 < NT)
                    stage_half(WT, Kld, n_base, (t + 1) * 64 + 32,
                               Bs + ((2 * (t + 1) + 1) & 3) * 8192, wave, lane);
            } else if (ph == 2) {
                if (t + 2 < NT) {
                    const int tt = t + 2;
                    const u16* sa = (tt < KsplitTile) ? A0 : A1;
                    const int cb = (tt < KsplitTile ? tt : tt - KsplitTile) * 64;
                    stage_half(sa, 1024, m_base, cb, As + ((2 * tt) & 3) * 8192, wave, lane);
                }
            } else {
                if (t + 2 < NT)
                    stage_half(WT, Kld, n_base, (t + 2) * 64,
                               Bs + ((2 * (t + 2)) & 3) * 8192, wave, lane);
            }

            // ---- ds_read fragments (swizzled: chunk ^= (row>>1)&3) ----
            const u16* Aslot = As + ((2 * t + ks) & 3) * 8192;
            const u16* Bslot = Bs + ((2 * t + ks) & 3) * 8192;
            if (mh == 0) {
                #pragma unroll
                for (int nj = 0; nj < 4; ++nj) {
                    const int row = wn * 64 + nj * 16 + l16;
                    bfr[nj] = *(const short8*)&Bslot[row * 32 + (((quad ^ (row >> 1)) & 3) << 3)];
                }
            }
            short8 af[4];
            #pragma unroll
            for (int mi = 0; mi < 4; ++mi) {
                const int row = wm * 128 + mh * 64 + mi * 16 + l16;
                af[mi] = *(const short8*)&Aslot[row * 32 + (((quad ^ (row >> 1)) & 3) << 3)];
            }

            __builtin_amdgcn_s_setprio(1);
            #pragma unroll
            for (int mi = 0; mi < 4; ++mi)
                #pragma unroll
                for (int nj = 0; nj < 4; ++nj)
                    acc[mh * 4 + mi][nj] = __builtin_amdgcn_mfma_f32_16x16x32_bf16(
                        af[mi], bfr[nj], acc[mh * 4 + mi][nj], 0, 0, 0);
            __builtin_amdgcn_s_setprio(0);

            // counted vmcnt before ph2's barrier: completes A/B(t,ks1),
            // leaves (t+1,ks0)+(t+1,ks1) in flight.
            if (ph == 1 && t + 1 < NT)
                asm volatile("s_waitcnt vmcnt(8)" ::: "memory");
        }
    }

    // ---- epilogue ----
    u16* op = (u16*)out;
    #pragma unroll
    for (int mi = 0; mi < 8; ++mi) {
        #pragma unroll
        for (int rg = 0; rg < 4; ++rg) {
            const int m = m_base + wm * 128 + mi * 16 + quad * 4 + rg;
            const int b = m / T, tk = m % T;   // T is compile-time -> magic mul
            #pragma unroll
            for (int nj = 0; nj < 4; ++nj) {
                const int col = n_base + wn * 64 + nj * 16 + l16;
                const int h = col >> 6, d = col & 63;
                if (EPI == 0) {
                    op[(((size_t)(b * 16 + h) * T + tk) << 6) + d] = f2bf(acc[mi][nj][rg]);
                } else {  // EPI == 2: head-transposed V^T
                    op[((size_t)(b * 16 + h) * 64 + d) * 1536 + tk] = f2bf(acc[mi][nj][rg]);
                }
            }
        }
    }
}

// ---------------------------------------------------------------------------
// bias body, 8-wave version: [6144,2048]@[2048,16] skinny MFMA, 16 tokens/wave
// Output prescaled by ATTN_SC (softmax scale+log2e fold for attn's 1-FMA score).
// ---------------------------------------------------------------------------
__device__ __forceinline__ void bias_body8(
    const u16* __restrict__ kvb, const u16* __restrict__ relb,
    const u16* __restrict__ wuvb, float* __restrict__ bias, int bblk)
{
    const int tid = threadIdx.x;
    const int wave = tid >> 6, lane = tid & 63;
    const int l16 = lane & 15, quad = lane >> 4;
    const int tBase = bblk * 128 + wave * 16;

    floatx4 acc = {0.f, 0.f, 0.f, 0.f};
    const u16* arow_kv  = kvb  + (size_t)(tBase + l16) * 1024;
    const u16* arow_rel = relb + (size_t)(tBase + l16) * 1024;
    const u16* brow     = wuvb + (size_t)l16 * 2048;

    for (int ks = 0; ks < 64; ks++) {
        const int k0 = ks * 32;
        const u16* ap = (k0 < 1024) ? (arow_kv + k0) : (arow_rel + k0 - 1024);
        short8 af = *(const short8*)(ap + quad * 8);
        short8 bf = *(const short8*)(brow + k0 + quad * 8);
        acc = __builtin_amdgcn_mfma_f32_16x16x32_bf16(af, bf, acc, 0, 0, 0);
    }
    for (int rg = 0; rg < 4; rg++) {
        const int tg = tBase + quad * 4 + rg;
        const int b = tg / 1536, t = tg % 1536;
        bias[((size_t)b * 16 + l16) * 1536 + t] = acc[rg] * ATTN_SC;
    }
}

// ---------------------------------------------------------------------------
// Fused projection dispatch v2: 304 blocks x 512 threads
//   (KR 96 | V 96 | Q 64 | bias 48), heavy (K=2048) blocks first.
// ---------------------------------------------------------------------------
__global__ __launch_bounds__(512) void fused_proj_v2(
    const u16* __restrict__ qb, const u16* __restrict__ kvb,
    const u16* __restrict__ relb,
    const u16* __restrict__ WqT, const u16* __restrict__ WkrT,
    const u16* __restrict__ WvT, const u16* __restrict__ wuvb,
    u16* __restrict__ Qh, u16* __restrict__ KRh, u16* __restrict__ Vt,
    float* __restrict__ bias)
{
    __shared__ __align__(128) u16 As[4 * 256 * 32];  // 64KB: 4-slot A ring
    __shared__ __align__(128) u16 Bs[4 * 256 * 32];  // 64KB: 4-slot B ring
    const int blk = blockIdx.x;
    if (blk < 96) {
        // KR: M=6144 K=2048 (kvb tiles 0..15, relb 16..31), T=1536
        gemm256_body<0, 1536>(kvb, relb, WkrT, KRh, 2048, 32, 16,
                              blk % 24, blk / 24, As, Bs);
    } else if (blk < 192) {
        const int i = blk - 96;   // V: M=6144 K=1024, head-transposed out
        gemm256_body<2, 1536>(kvb, kvb, WvT, Vt, 1024, 16, 99,
                              i % 24, i / 24, As, Bs);
    } else if (blk < 256) {
        const int i = blk - 192;  // Q: M=4096 K=1024, T=1024
        gemm256_body<0, 1024>(qb, qb, WqT, Qh, 1024, 16, 99,
                              i % 16, i / 16, As, Bs);
    } else {
        bias_body8(kvb, relb, wuvb, bias, blk - 256);
    }
}

// ---------------------------------------------------------------------------
// Output GEMM, split-K=2 (grid (32,8,2) = 512 blocks = 2/CU): raw fp32
// partials to outp + z*4M; LayerNorm sums partials + residual.
// ---------------------------------------------------------------------------
__global__ __launch_bounds__(256) void out_gemm(
    const u16* __restrict__ ctx, const u16* __restrict__ WoT,
    float* __restrict__ outp)
{
    __shared__ u16 smem[2 * 128 * 32];
    const int z = blockIdx.z;
    gemm_body<3>(ctx, nullptr, WoT,
                 outp + (size_t)z * 4 * 1024 * 1024, 1024,
                 z * 512, z * 512 + 512, 1024, 1024,
                 blockIdx.x, blockIdx.y, smem, smem + 128 * 32);
}

// ---------------------------------------------------------------------------
// Flash attention v5 (round-16): 128 q-rows/block, 8 waves x 512 threads.
// 3-slot K/V ring + counted vmcnt(2) + raw s_barrier per tile: stage(t+2)
// issued at tile t, completed by the vmcnt(2) at end of tile t+1 -> each
// staged tile gets 2 compute phases; main loop never drains vmcnt to 0.
// Heavy-first: qblk = 7 - blk>>6 (24-tile blocks dispatch first).
// LDS 64KB (3x8K K + 3x8K V + 16K P) -> 2 blocks/CU.
// Exact-exp softmax; swapped QK^T; XOR swizzle chunk^=(row&7) on K/V/P.
// ---------------------------------------------------------------------------
__global__ __launch_bounds__(512, 4) void attn_kernel(
    const u16* __restrict__ Qh,   // [B][H][1024][64]
    const u16* __restrict__ KRh,  // [B][H][1536][64]
    const u16* __restrict__ Vt,   // [B][H][64][1536]
    const float* __restrict__ bias, // [B][H][1536], prescaled by ATTN_SC
    u16* __restrict__ ctx)        // [B][1024][1024] token-major
{
    const int blk  = blockIdx.x;
    const int hb   = blk & 63;          // XCD-residue swizzle on (b,h)
    const int qblk = 7 - (blk >> 6);    // heavy blocks (qblk 7: 24 tiles) first
    const int b = hb >> 4, h = hb & 15;
    const int tid = threadIdx.x;
    const int wave = tid >> 6, lane = tid & 63;   // wave 0..7
    const int l16 = lane & 15, quad = lane >> 4;
    const int q0w = qblk * 128 + wave * 16;   // this wave's 16 q-rows

    const u16* Qp = Qh  + (size_t)hb * 1024 * 64;
    const u16* Kp = KRh + (size_t)hb * 1536 * 64;
    const u16* Vp = Vt  + (size_t)hb * 64 * 1536;
    const float* bp = bias + (size_t)hb * 1536;

    __shared__ __align__(128) u16 Kbuf[3][64 * 64];  // 24KB  [key][d] swz
    __shared__ __align__(128) u16 Vbuf[3][64 * 64];  // 24KB  [d][key] swz
    __shared__ __align__(128) u16 Ps[8][16 * 64];    // 16KB per-wave P, swz

    // stage: each wave owns 8 K rows + 8 V rows (1 gl_lds each = 8 rows).
    // linear LDS dest; source chunk pre-swizzled: phys(row,chunk) holds
    // global (row, chunk ^ (row&7)); row&7 == lane>>3 within each 8-row grp.
    const int srow = lane >> 3;                   // 0..7
    const int scol = ((lane & 7) ^ srow) * 8;     // swizzled source col (elems)

    const floatx4 zf = {0.f, 0.f, 0.f, 0.f};
    floatx4 accO[4];
    float lsum = 0.f;
    #pragma unroll
    for (int j = 0; j < 4; j++) accO[j] = zf;

    short8 aq[2];
    #pragma unroll
    for (int ks = 0; ks < 2; ks++)
        aq[ks] = *(const short8*)
            &Qp[(size_t)(q0w + l16) * 64 + ks * 32 + quad * 8];

    const int nkt = 2 * qblk + 10;   // tiles cover keys 0 .. qblk*128+127+512

    // prologue: stage tiles 0,1 into slots 0,1; vmcnt(2) completes tile 0.
    {
        const int r0 = wave * 8;
        gl_lds16(Kp + (size_t)(r0 + srow) * 64 + scol,         &Kbuf[0][r0 * 64]);
        gl_lds16(Vp + (size_t)(r0 + srow) * 1536 + scol,       &Vbuf[0][r0 * 64]);
        gl_lds16(Kp + (size_t)(64 + r0 + srow) * 64 + scol,    &Kbuf[1][r0 * 64]);
        gl_lds16(Vp + (size_t)(r0 + srow) * 1536 + 64 + scol,  &Vbuf[1][r0 * 64]);
    }
    asm volatile("s_waitcnt vmcnt(2)" ::: "memory");
    __builtin_amdgcn_s_barrier();

    for (int kt = 0; kt < nkt; kt++) {
        const int k0 = kt * 64;
        const int cur = kt % 3;

        // ---- stage tile kt+2 into slot (kt+2)%3 (freed at end of kt-1) ----
        if (kt + 2 < nkt) {
            const int k2 = (kt + 2) * 64;
            const int s2 = (kt + 2) % 3;
            const int r0 = wave * 8;
            gl_lds16(Kp + (size_t)(k2 + r0 + srow) * 64 + scol,
                     &Kbuf[s2][r0 * 64]);
            gl_lds16(Vp + (size_t)(r0 + srow) * 1536 + k2 + scol,
                     &Vbuf[s2][r0 * 64]);
        }

        // ---- bias for this tile (global, L2/L3-hit; latency overlaps reads)
        float4 bc[4];
        #pragma unroll
        for (int n = 0; n < 4; n++)
            bc[n] = *(const float4*)&bp[k0 + n * 16 + quad * 4];

        // ---- K frags from LDS (swizzled): row = n*16+l16, chunk = ks*4+quad
        const u16* Kb = &Kbuf[cur][0];
        const u16* Vb = &Vbuf[cur][0];
        short8 bk[4][2];
        #pragma unroll
        for (int n = 0; n < 4; n++)
            #pragma unroll
            for (int ks = 0; ks < 2; ks++)
                bk[n][ks] = *(const short8*)
                    &Kb[(n * 16 + l16) * 64 + (((ks * 4 + quad) ^ (l16 & 7)) * 8)];

        // ---- QK^T (swapped): lane q = l16, keys = n*16 + quad*4 + rg
        floatx4 accS[4];
        #pragma unroll
        for (int n = 0; n < 4; n++) {
            accS[n] = zf;
            #pragma unroll
            for (int ks = 0; ks < 2; ks++)
                accS[n] = __builtin_amdgcn_mfma_f32_16x16x32_bf16(
                    bk[n][ks], aq[ks], accS[n], 0, 0, 0);
        }

        // ---- softmax + P pack into swizzled per-wave LDS scratch
        const int qg = q0w + l16;
        const bool domask = (k0 + 63 > q0w + 15 + 512);
        const int lim = qg + 512 - k0;
        char* Pbase = (char*)&Ps[wave][0];
        #pragma unroll
        for (int n = 0; n < 4; n++) {
            const int limn = lim - n * 16 - quad * 4;
            const float* bcn = (const float*)&bc[n];
            float pv[4];
            #pragma unroll
            for (int rg = 0; rg < 4; rg++) {
                float s = fmaf(accS[n][rg], ATTN_SC, bcn[rg]);
                if (domask && rg > limn) s = -1e30f;
                float pe;
                asm("v_exp_f32 %0, %1" : "=v"(pe) : "v"(s));
                lsum += pe;
                pv[rg] = pe;
            }
            unsigned w0, w1;
            asm("v_cvt_pk_bf16_f32 %0, %1, %2" : "=v"(w0) : "v"(pv[0]), "v"(pv[1]));
            asm("v_cvt_pk_bf16_f32 %0, %1, %2" : "=v"(w1) : "v"(pv[2]), "v"(pv[3]));
            // logical byte = l16*128 + n*32 + quad*8 ; phys ^= (l16&7)<<4
            unsigned* pw = (unsigned*)(Pbase +
                (((l16 * 128 + n * 32 + quad * 8)) ^ ((l16 & 7) << 4)));
            pw[0] = w0; pw[1] = w1;
        }

        // ---- PV: A frag = P row l16 (swizzled b128), B frag = V from LDS
        short8 ap[2];
        #pragma unroll
        for (int ks = 0; ks < 2; ks++)
            ap[ks] = *(const short8*)(Pbase +
                (((l16 * 128 + ks * 64 + quad * 16)) ^ ((l16 & 7) << 4)));
        #pragma unroll
        for (int j = 0; j < 4; j++) {
            #pragma unroll
            for (int ks = 0; ks < 2; ks++) {
                short8 bv = *(const short8*)
                    &Vb[(j * 16 + l16) * 64 + (((ks * 4 + quad) ^ (l16 & 7)) * 8)];
                accO[j] = __builtin_amdgcn_mfma_f32_16x16x32_bf16(
                    ap[ks], bv, accO[j], 0, 0, 0);
            }
        }

        // ---- counted vmcnt + barrier: completes stage(kt+1), leaves
        // stage(kt+2) in flight. No wait/barrier after the last tile.
        if (kt + 1 < nkt) {
            if (kt + 2 < nkt) asm volatile("s_waitcnt vmcnt(2)" ::: "memory");
            else              asm volatile("s_waitcnt vmcnt(0)" ::: "memory");
            __builtin_amdgcn_s_barrier();
        }
    }

    // lsum quad-reduce: every lane gets full sum for q = l16
    {
        float s = lsum;
        s += __shfl_xor(s, 16, 64);
        s += __shfl_xor(s, 32, 64);
        lsum = s;
    }
    float ltr[4];
    #pragma unroll
    for (int rg = 0; rg < 4; rg++)
        ltr[rg] = __shfl(lsum, quad * 4 + rg, 16);   // sum for q = quad*4+rg

    #pragma unroll
    for (int j = 0; j < 4; j++)
        #pragma unroll
        for (int rg = 0; rg < 4; rg++) {
            const int q = q0w + quad * 4 + rg;
            const int d = j * 16 + l16;
            ctx[((size_t)b * 1024 + q) * 1024 + h * 64 + d] =
                f2bf(accO[j][rg] / ltr[rg]);
        }
}

// ---------------------------------------------------------------------------
// LayerNorm over (partial0 + partial1 + residual query): fp32 -> fp32 d_out
// ---------------------------------------------------------------------------
__global__ __launch_bounds__(256) void ln_kernel(
    const float* __restrict__ x0, const float* __restrict__ x1,
    const float* __restrict__ q,
    const float* __restrict__ gamma, const float* __restrict__ beta,
    float* __restrict__ out)
{
    const int row = blockIdx.x;
    const int tid = threadIdx.x;
    const size_t base = (size_t)row * 1024 + tid * 4;
    float4 a = *(const float4*)&x0[base];
    float4 c = *(const float4*)&x1[base];
    float4 r = *(const float4*)&q[base];
    float4 v;
    v.x = a.x + c.x + r.x; v.y = a.y + c.y + r.y;
    v.z = a.z + c.z + r.z; v.w = a.w + c.w + r.w;
    float s  = v.x + v.y + v.z + v.w;
    float ss = v.x * v.x + v.y * v.y + v.z * v.z + v.w * v.w;
    for (int off = 1; off < 64; off <<= 1) {
        s  += __shfl_xor(s, off, 64);
        ss += __shfl_xor(ss, off, 64);
    }
    __shared__ float sm[8];
    const int wave = tid >> 6, lane = tid & 63;
    if (lane == 0) { sm[wave] = s; sm[4 + wave] = ss; }
    __syncthreads();
    s  = sm[0] + sm[1] + sm[2] + sm[3];
    ss = sm[4] + sm[5] + sm[6] + sm[7];
    const float mu  = s * (1.f / 1024.f);
    const float var = ss * (1.f / 1024.f) - mu * mu;
    const float inv = rsqrtf(var + 1e-5f);
    float* op = out + (size_t)row * 1024;
    const float* ve = &v.x;
    for (int j = 0; j < 4; j++) {
        const int c2 = tid * 4 + j;
        op[c2] = (ve[j] - mu) * inv * gamma[c2] + beta[c2];
    }
}

// ---------------------------------------------------------------------------
extern "C" void kernel_launch(void* const* d_in, const int* in_sizes, int n_in,
                              void* d_out, int out_size, void* d_ws, size_t ws_size,
                              hipStream_t stream)
{
    const float* query     = (const float*)d_in[0];
    const float* key_value = (const float*)d_in[1];
    const float* relative  = (const float*)d_in[2];
    // d_in[3] = mask: analytic (j <= i+512), unused
    const float* Wq = (const float*)d_in[4];
    const float* Wk = (const float*)d_in[5];
    const float* Wv = (const float*)d_in[6];
    const float* Wr = (const float*)d_in[7];
    const float* Wo = (const float*)d_in[8];
    const float* u  = (const float*)d_in[9];
    const float* v  = (const float*)d_in[10];
    const float* gamma = (const float*)d_in[11];
    const float* beta  = (const float*)d_in[12];

    char* wsp = (char*)d_ws;
    auto alloc = [&](size_t bytes) -> char* {
        char* p = wsp; wsp += (bytes + 255) & ~(size_t)255; return p;
    };
    u16*   qb   = (u16*)alloc((size_t)4 * 1024 * 1024 * 2);
    u16*   kvb  = (u16*)alloc((size_t)4 * 1536 * 1024 * 2);
    u16*   relb = (u16*)alloc((size_t)4 * 1536 * 1024 * 2);
    u16*   WqT  = (u16*)alloc((size_t)1024 * 1024 * 2);
    u16*   WkrT = (u16*)alloc((size_t)1024 * 2048 * 2);
    u16*   WvT  = (u16*)alloc((size_t)1024 * 1024 * 2);
    u16*   WoT  = (u16*)alloc((size_t)1024 * 1024 * 2);
    u16*   wuvb = (u16*)alloc((size_t)16 * 2048 * 2);
    u16*   Qh   = (u16*)alloc((size_t)4 * 16 * 1024 * 64 * 2);
    u16*   KRh  = (u16*)alloc((size_t)4 * 16 * 1536 * 64 * 2);
    u16*   Vt   = (u16*)alloc((size_t)4 * 16 * 64 * 1536 * 2);
    float* bias = (float*)alloc((size_t)4 * 16 * 1536 * 4);
    u16*   ctx  = (u16*)alloc((size_t)4 * 1024 * 1024 * 2);
    float* outp = (float*)alloc((size_t)2 * 4 * 1024 * 1024 * 4);  // 2 split-K partials

    const dim3 tb(256);
    prep_kernel<<<dim3(9536), tb, 0, stream>>>(
        query, qb, key_value, kvb, relative, relb,
        Wq, Wk, Wr, Wv, Wo, WqT, WkrT, WvT, WoT, u, v, wuvb);

    fused_proj_v2<<<dim3(304), dim3(512), 0, stream>>>(
        qb, kvb, relb, WqT, WkrT, WvT, wuvb, Qh, KRh, Vt, bias);

    attn_kernel<<<dim3(512), dim3(512), 0, stream>>>(Qh, KRh, Vt, bias, ctx);

    out_gemm<<<dim3(32, 8, 2), tb, 0, stream>>>(ctx, WoT, outp);
    ln_kernel<<<4096, tb, 0, stream>>>(
        outp, outp + (size_t)4 * 1024 * 1024, query, gamma, beta, (float*)d_out);
}